// Round 3
// baseline (131061.633 us; speedup 1.0000x reference)
//
#include <hip/hip_runtime.h>
#include <math.h>

#define NB 32
#define NN 32
#define NSTEPS 600
#define NT1 601
#define NSI 10
#define NH 75
#define NU 80      // padded u (8 groups x 10)
#define NKB 20     // padded k-blocks of 4 (k padded 75 -> 80)
#define NIB 16     // sibling blocks per batch element

#define ICM2IFS 2.99792458e-05
#define KBOLTZ 0.6950389f
#define TWO_PI 6.283185307179586476925286766559

__device__ __forceinline__ float elu1(float x) { return x > 0.f ? x : (__expf(x) - 1.f); }

// ---------------------------------------------------------------------------
// Phase A: batched 32x32 symmetric eigensolver (parallel cyclic Jacobi).
// Unchanged.
// ---------------------------------------------------------------------------
__global__ __launch_bounds__(64) void eigh_kernel(const float* __restrict__ Hf,
                                                  float* __restrict__ E_all,
                                                  float* __restrict__ CT_all)
{
    __shared__ double A[NN][NN + 1];
    __shared__ float  V[NN][NN + 1];
    __shared__ double csC[16], csS[16];
    __shared__ int   prC[16], qrC[16];
    __shared__ double redv;
    __shared__ int   rankl[NN];

    const int idx = blockIdx.x;      // b*601 + t
    const int tid = threadIdx.x;
    const float* Hp = Hf + (size_t)idx * (NN * NN);

    for (int e = tid; e < NN * NN; e += 64) {
        A[e >> 5][e & 31] = (double)Hp[e];
        V[e >> 5][e & 31] = ((e >> 5) == (e & 31)) ? 1.f : 0.f;
    }
    __syncthreads();

    double part = 0.0;
    for (int e = tid; e < NN * NN; e += 64) { double v = A[e >> 5][e & 31]; part += v * v; }
    #pragma unroll
    for (int off = 32; off > 0; off >>= 1) part += __shfl_down(part, off);
    if (tid == 0) redv = part;
    __syncthreads();
    const double tol2 = 1e-20 * redv;

    for (int sweep = 0; sweep < 10; ++sweep) {
        for (int r = 0; r < NN - 1; ++r) {
            if (tid < 16) {
                int m = tid, p, q;
                if (m == 0) { p = 0; q = 1 + (r % 31); }
                else { p = 1 + ((m + r) % 31); q = 1 + ((31 - m + r) % 31); }
                double apq = A[p][q];
                double c = 1.0, sn = 0.0;
                if (apq != 0.0) {
                    double theta = 0.5 * (A[q][q] - A[p][p]) / apq;
                    double tt = 1.0 / (fabs(theta) + sqrt(theta * theta + 1.0));
                    if (theta < 0.0) tt = -tt;
                    c = 1.0 / sqrt(tt * tt + 1.0);
                    sn = tt * c;
                }
                csC[m] = c; csS[m] = sn; prC[m] = p; qrC[m] = q;
            }
            __syncthreads();
            #pragma unroll
            for (int it = 0; it < 8; ++it) {          // rows: A <- J^T A
                int task = tid + it * 64;
                int m = task >> 5, jc = task & 31;
                int p = prC[m], q = qrC[m];
                double c = csC[m], sn = csS[m];
                double ap = A[p][jc], aq = A[q][jc];
                A[p][jc] = c * ap - sn * aq;
                A[q][jc] = sn * ap + c * aq;
            }
            __syncthreads();
            #pragma unroll
            for (int it = 0; it < 16; ++it) {         // cols: A <- A J (f64), V <- V J (f32)
                int task = tid + it * 64;
                int m = (task >> 5) & 15, ir = task & 31;
                int p = prC[m], q = qrC[m];
                if (task < 512) {
                    double c = csC[m], sn = csS[m];
                    double aip = A[ir][p], aiq = A[ir][q];
                    A[ir][p] = c * aip - sn * aiq;
                    A[ir][q] = sn * aip + c * aiq;
                } else {
                    float cf = (float)csC[m], sf = (float)csS[m];
                    float vip = V[ir][p], viq = V[ir][q];
                    V[ir][p] = cf * vip - sf * viq;
                    V[ir][q] = sf * vip + cf * viq;
                }
            }
            __syncthreads();
        }
        if (sweep >= 3) {
            double o = 0.0;
            for (int e = tid; e < NN * NN; e += 64) {
                int i2 = e >> 5, j2 = e & 31;
                double v = A[i2][j2];
                o += (i2 != j2) ? v * v : 0.0;
            }
            #pragma unroll
            for (int off = 32; off > 0; off >>= 1) o += __shfl_down(o, off);
            if (tid == 0) redv = o;
            __syncthreads();
            if (redv <= tol2) break;
        }
    }
    __syncthreads();

    if (tid < NN) {
        double ei = A[tid][tid];
        int rk = 0;
        for (int j2 = 0; j2 < NN; ++j2) {
            double ej = A[j2][j2];
            rk += (ej < ei || (ej == ei && j2 < tid)) ? 1 : 0;
        }
        rankl[tid] = rk;
        E_all[(size_t)idx * NN + rk] = (float)ei;
    }
    __syncthreads();
    float* ct = CT_all + (size_t)idx * NN * NN;
    for (int e = tid; e < NN * NN; e += 64) {
        int col = e >> 5, m2 = e & 31;
        ct[(size_t)rankl[col] * NN + m2] = V[m2][col];
    }
}

// ---------------------------------------------------------------------------
// Phase A2: kk[b,s,j] = argmax_i S[b,s,i,j]^2 (first index on ties)
// ---------------------------------------------------------------------------
__global__ __launch_bounds__(256) void kk_kernel(const float* __restrict__ CT_all,
                                                 int* __restrict__ kk_all)
{
    __shared__ float Ct[NN][NN + 1], Cp[NN][NN + 1], S[NN][NN + 1];
    const int blk = blockIdx.x;                // b*600 + (s-1)
    const int b = blk / NSTEPS, s = blk % NSTEPS + 1;
    const int tid = threadIdx.x;
    const float* ctg = CT_all + ((size_t)b * NT1 + s) * (NN * NN);
    const float* cpg = CT_all + ((size_t)b * NT1 + s - 1) * (NN * NN);
    for (int e = tid; e < NN * NN; e += 256) {
        Ct[e >> 5][e & 31] = ctg[e];
        Cp[e >> 5][e & 31] = cpg[e];
    }
    __syncthreads();
    for (int e = tid; e < NN * NN; e += 256) {
        int i = e >> 5, j = e & 31;
        float acc = 0.f;
        for (int m = 0; m < NN; ++m) acc += Ct[i][m] * Cp[j][m];
        S[i][j] = acc;
    }
    __syncthreads();
    if (tid < NN) {
        const int j = tid;
        float best = -1.f; int bi = 0;
        for (int i = 0; i < NN; ++i) {
            float v = S[i][j]; v *= v;
            if (v > best) { best = v; bi = i; }
        }
        kk_all[(size_t)blk * NN + j] = bi;
    }
}

// ---------------------------------------------------------------------------
// Pack weights: Wp[ug 8][kb 20][kp 4][12] (10 u + 2 pad, 16B rows; zero pad).
// ---------------------------------------------------------------------------
__global__ void wtrans_kernel(const float* __restrict__ W1, const float* __restrict__ b1,
                              const float* __restrict__ W2, const float* __restrict__ W3,
                              const float* __restrict__ b2, const float* __restrict__ b3,
                              const float* __restrict__ W4,
                              float* __restrict__ W2p, float* __restrict__ W3p,
                              float4* __restrict__ L1W4, float4* __restrict__ L1B4,
                              float* __restrict__ bpad)
{
    const int tid = threadIdx.x;
    const int tot = 8 * NKB * 4 * 12;          // 7680
    for (int e = tid; e < tot; e += 256) {
        int ug = e / (NKB * 4 * 12);
        int kb = (e / (4 * 12)) % NKB;
        int kp = (e / 12) & 3;
        int uu = e % 12;
        int u = ug * 10 + uu;
        int k = kb * 4 + kp;
        float v2 = 0.f, v3 = 0.f;
        if (uu < 10 && u < NH && k < NH) {
            v2 = W2[u * NH + k];
            v3 = W3[u * NH + k];
        }
        W2p[e] = v2; W3p[e] = v3;
    }
    if (tid < NU) {
        if (tid < NH) {
            const float* w = W1 + tid * 8;
            L1W4[tid] = make_float4(w[0], w[1], w[2], w[7]);
            L1B4[tid] = make_float4(w[3], w[4], w[5], b1[tid]);
            bpad[tid]          = b2[tid];
            bpad[NU + tid]     = b3[tid];
            bpad[2 * NU + tid] = W4[tid];
        } else {
            L1W4[tid] = make_float4(0.f, 0.f, 0.f, 0.f);
            L1B4[tid] = make_float4(0.f, 0.f, 0.f, 0.f);
            bpad[tid] = 0.f; bpad[NU + tid] = 0.f; bpad[2 * NU + tid] = 0.f;
        }
    }
}

// ---------------------------------------------------------------------------
// Phase B persistent kernel. R13 = R12 structure (16 siblings x 64 pairs,
// 2 blocks/CU, in-register column correction, parallel fp64 tail,
// features-in-spin-window) with the POLL STORM fixed:
//   * R12 regression root-cause: s_sleep(1) spin -> each block polled the
//     sibling counter every ~100cyc through the coherence point; 512 blocks
//     x 20M polls/s x ~256B TCC traffic = the measured 2.6-3.3 TB/s /
//     403 GB per dispatch. Feedback loop: poll traffic slowed the exchange,
//     which lengthened spins, which made more polls (255us/step equilibrium).
//   * Fix 1: poll once, then s_sleep(16) (~1024cyc) between polls -> ~20x
//     lower poll rate at source; exit latency ~0.2-0.4us on a ~10us step.
//   * Fix 2: arrival add moved INTO wave 0 right after its vmcnt(0) drain
//     (wave 0 is the only S2-storing wave) -> signal leaves ~1-2us earlier
//     and one __syncthreads is deleted.
//   * Fix 3: S2T readback as 8B coherent loads (half the sc0sc1 ops).
// ---------------------------------------------------------------------------
__global__ __launch_bounds__(512, 4) void persist_kernel(
    const float* __restrict__ E_all, const float* __restrict__ CT_all,
    const int* __restrict__ kk_all, const float* __restrict__ psi0,
    const float* __restrict__ Tarr, const float* __restrict__ ErA,
    const float* __restrict__ ctA, const float* __restrict__ dtA,
    const float* __restrict__ W2p, const float* __restrict__ W3p,
    const float4* __restrict__ L1W4g, const float4* __restrict__ L1B4g,
    const float* __restrict__ bpad, const float* __restrict__ b4v,
    float* __restrict__ S2T_g, unsigned int* __restrict__ cnt,
    float* __restrict__ out)
{
    extern __shared__ __align__(16) float dyn[];
    float4* L1Wl = (float4*)dyn;                // 80 f4
    float4* L1Bl = L1Wl + NU;                   // 80 f4
    float* cst  = (float*)(L1Bl + NU);          // 80
    float* b2l  = cst + NU;                     // 80
    float* b3l  = b2l + NU;                     // 80
    float* W4l  = b3l + NU;                     // 80
    float* hbuf = W4l + NU;                     // 80*64 = 5120 floats
    float (*S2T)[NN + 4] = (float(*)[NN + 4])hbuf;   // aliases hbuf (disjoint lifetime)

    __shared__ float CpN[2][NN][NN + 4];
    __shared__ float4 featS[64];                // {DE, ratio, Sv, ex} per pair
    __shared__ float a4b2[8][64];
    __shared__ float EL[2][NN];
    __shared__ int   kkL[2][NN];
    __shared__ double phre[NN], phim[NN], redl[NN], nreS[NN], nimS[NN];
    __shared__ float phi2l[NN];

    const int tid  = threadIdx.x;
    const int b    = blockIdx.x >> 4;           // sibling sets are CONSECUTIVE idx
    const int iblk = blockIdx.x & 15;
    const int j0   = iblk * 2;                  // owns columns j0, j0+1
    const int ug   = __builtin_amdgcn_readfirstlane(tid >> 6);  // uniform wave id
    const int rg   = tid & 63;                  // pair index r: i = r&31, j = j0+(r>>5)
    const int U    = ug * 10;

    const float kbt = KBOLTZ * Tarr[b];
    const float er  = ErA[b];
    const float cti = ctA[b];
    const double dtb = (double)dtA[b];
    const float b4s = b4v[0];

    const float4* W2g = (const float4*)(W2p + (size_t)ug * (NKB * 48));
    const float4* W3g = (const float4*)(W3p + (size_t)ug * (NKB * 48));

    // ---- stage small loop-invariant tables into LDS (once) ----
    if (tid < NU) {
        L1Wl[tid] = L1W4g[tid];
        L1Bl[tid] = L1B4g[tid];
        b2l[tid] = bpad[tid];
        b3l[tid] = bpad[NU + tid];
        W4l[tid] = bpad[2 * NU + tid];
    }
    __syncthreads();
    if (tid < NU) {     // per-b constant part of layer-1 preactivation
        float4 lb = L1Bl[tid];
        cst[tid] = lb.w + lb.x * kbt + lb.y * er + lb.z * cti;
    }

    // ---- prime: C_0, C_1, E[0], E[1], kk[0]; init phiB; featS for s=1 ----
    {
        const float* c0g = CT_all + (size_t)b * NT1 * NN * NN;
        const float* c1g = c0g + NN * NN;
        for (int e = tid; e < NN * NN; e += 512) {
            CpN[0][e >> 5][e & 31] = c0g[e];
            CpN[1][e >> 5][e & 31] = c1g[e];
        }
        if (tid < NN) {
            EL[0][tid] = E_all[((size_t)b * NT1 + 0) * NN + tid];
            EL[1][tid] = E_all[((size_t)b * NT1 + 1) * NN + tid];
            kkL[1][tid] = kk_all[(size_t)b * NSTEPS * NN + tid];
        }
        __syncthreads();
        if (tid < NN) {
            const int i = tid;
            double acc = 0.0;
            for (int j = 0; j < NN; ++j) acc += (double)CpN[0][i][j] * (double)psi0[b * NN + j];
            phre[i] = acc; phim[i] = 0.0;
            phi2l[i] = (float)(acc * acc);
            if (iblk == 0) {
                float p0 = psi0[b * NN + i];
                out[((size_t)b * 61) * NN + i] = p0 * p0;
            }
        }
        __syncthreads();
        {   // features for step 1 (curS = 1): Sv/DE/ex, 8 lanes per pair
            const int r = tid >> 3, c = tid & 7;
            const int i = r & 31, j = j0 + (r >> 5);
            float Sv = 0.f;
            #pragma unroll
            for (int m = c; m < NN; m += 8)
                Sv += CpN[1][i][m] * CpN[0][j][m];
            Sv += __shfl_xor(Sv, 1); Sv += __shfl_xor(Sv, 2); Sv += __shfl_xor(Sv, 4);
            if (c == 0) {
                const int kj = kkL[1][j];
                const float DE = (i == kj) ? 0.f : (EL[1][i] - EL[0][j]);
                featS[r] = make_float4(DE, 100.f, Sv, __expf(DE / kbt));
            }
        }
        __syncthreads();
        if (tid < 64) {     // ratio for step 1
            const int i = tid & 31, j = j0 + (tid >> 5);
            const float p_i = phi2l[i], p_j = phi2l[j];
            featS[tid].y = (p_j > 0.01f * p_i) ? (p_i / p_j) : 100.f;
        }
    }

    for (int t = 1; t <= NSTEPS; ++t) {
        __syncthreads();                        // featS / phi2l visible
        const int cur = t & 1;

        // ---- issue prefetch loads for step t+1 (retire during MLP) ----
        float2 cpre = make_float2(0.f, 0.f);
        float  epre = 0.f;
        int    kpre = 0;
        if (t < NSTEPS) {
            const float* c1g = CT_all + ((size_t)b * NT1 + t + 1) * (NN * NN);
            cpre = ((const float2*)c1g)[tid];
            if (tid < NN) epre = E_all[((size_t)b * NT1 + t + 1) * NN + tid];
            else if (tid < 2 * NN) kpre = kk_all[((size_t)b * NSTEPS + t) * NN + (tid - NN)];
        }

        // ---- layer 1 (features -> h1), tile 10u x 1r ----
        {
            float4 f0 = featS[rg];
            #pragma unroll
            for (int u = 0; u < 10; ++u) {
                float4 wv = L1Wl[U + u];
                float c = cst[U + u];
                hbuf[(U + u) * 64 + rg] =
                    elu1(c + wv.x * f0.x + wv.y * f0.y + wv.z * f0.z + wv.w * f0.w);
            }
        }
        __syncthreads();

        // ---- layer 2 (h1 -> h2): weights via wave-uniform scalar loads ----
        float acc[10];
        #pragma unroll
        for (int u = 0; u < 10; ++u) acc[u] = b2l[U + u];
        for (int kb = 0; kb < NKB; ++kb) {
            float4 wv[12];
            float hv[4];
            #pragma unroll
            for (int m = 0; m < 12; ++m) wv[m] = W2g[kb * 12 + m];   // uniform -> s_load
            #pragma unroll
            for (int kk = 0; kk < 4; ++kk)
                hv[kk] = hbuf[(kb * 4 + kk) * 64 + rg];
            #pragma unroll
            for (int kk = 0; kk < 4; ++kk) {
                const float* wf = (const float*)&wv[kk * 3];
                #pragma unroll
                for (int u = 0; u < 10; ++u) acc[u] += wf[u] * hv[kk];
            }
        }
        __syncthreads();    // all reads of h1 done before overwriting hbuf
        #pragma unroll
        for (int u = 0; u < 10; ++u) hbuf[(U + u) * 64 + rg] = elu1(acc[u]);
        __syncthreads();

        // ---- layer 3 (h2 -> h3 in registers) ----
        #pragma unroll
        for (int u = 0; u < 10; ++u) acc[u] = b3l[U + u];
        for (int kb = 0; kb < NKB; ++kb) {
            float4 wv[12];
            float hv[4];
            #pragma unroll
            for (int m = 0; m < 12; ++m) wv[m] = W3g[kb * 12 + m];   // uniform -> s_load
            #pragma unroll
            for (int kk = 0; kk < 4; ++kk)
                hv[kk] = hbuf[(kb * 4 + kk) * 64 + rg];
            #pragma unroll
            for (int kk = 0; kk < 4; ++kk) {
                const float* wf = (const float*)&wv[kk * 3];
                #pragma unroll
                for (int u = 0; u < 10; ++u) acc[u] += wf[u] * hv[kk];
            }
        }
        // ---- layer 4 partials ----
        {
            float p4 = 0.f;
            #pragma unroll
            for (int u = 0; u < 10; ++u) p4 += W4l[U + u] * elu1(acc[u]);
            a4b2[ug][rg] = p4;
        }
        __syncthreads();

        // ---- finalize corr, IN-REGISTER column correction, coherent store,
        //      and EARLY arrival signal (all inside wave 0) ----
        if (tid < 64) {
            const int r = tid;
            const int i = r & 31;
            const int j = j0 + (r >> 5);
            float a4 = b4s;
            #pragma unroll
            for (int g = 0; g < 8; ++g) a4 += a4b2[g][r];
            const float corr = elu1(a4) + 1.f;
            float s2v = featS[r].z * corr;
            const int kj = kkL[cur][j];
            double v = (double)s2v;
            double cd = (i == kj) ? 0.0 : v * v;
            cd += __shfl_xor(cd, 1);  cd += __shfl_xor(cd, 2);
            cd += __shfl_xor(cd, 4);  cd += __shfl_xor(cd, 8);
            cd += __shfl_xor(cd, 16);
            if (i == kj) {
                double nrm = fabs(v); nrm = (nrm > 0.0) ? nrm : 1.0;
                double rem = 1.0 - cd;
                s2v = (float)((rem > 0.0) ? (sqrt(rem) * v / nrm) : v);
            }
            __hip_atomic_store(&S2T_g[(((size_t)cur * NB + b) * NN + j) * NN + i],
                               s2v, __ATOMIC_RELAXED, __HIP_MEMORY_SCOPE_AGENT);
            asm volatile("s_waitcnt vmcnt(0)" ::: "memory");    // drain coherent stores
            if (tid == 0)       // wave 0 stored everything -> signal NOW
                __hip_atomic_fetch_add(cnt + (size_t)b * NSTEPS + (t - 1), 1u,
                                       __ATOMIC_RELAXED, __HIP_MEMORY_SCOPE_AGENT);
        }

        // ---- commit prefetch into dead ping-pong slots (no sync needed:
        //      writes [1-cur] slots, wave 0 above reads only [cur]) ----
        if (t < NSTEPS) {
            const int e0 = tid * 2;
            CpN[1 - cur][e0 >> 5][e0 & 31] = cpre.x;
            CpN[1 - cur][e0 >> 5][(e0 & 31) + 1] = cpre.y;
            if (tid < NN) EL[1 - cur][tid] = epre;
            else if (tid < 2 * NN) kkL[1 - cur][tid - NN] = kpre;
        }
        __syncthreads();

        // ---- features for t+1 (Sv/DE/ex) — hidden inside the spin window ----
        if (t < NSTEPS) {
            const int curS = 1 - cur;
            const int r = tid >> 3, c = tid & 7;
            const int i = r & 31, j = j0 + (r >> 5);
            float Sv = 0.f;
            #pragma unroll
            for (int m = c; m < NN; m += 8)
                Sv += CpN[curS][i][m] * CpN[1 - curS][j][m];
            Sv += __shfl_xor(Sv, 1); Sv += __shfl_xor(Sv, 2); Sv += __shfl_xor(Sv, 4);
            if (c == 0) {
                const int kj = kkL[curS][j];
                const float DE = (i == kj) ? 0.f : (EL[curS][i] - EL[1 - curS][j]);
                featS[r] = make_float4(DE, 100.f, Sv, __expf(DE / kbt));
            }
        }

        // ---- sibling barrier: poll once, then sleep-backoff (POLL-STORM FIX)
        if (tid == 0) {
            const unsigned int* c = cnt + (size_t)b * NSTEPS + (t - 1);
            while (__hip_atomic_load(c, __ATOMIC_RELAXED, __HIP_MEMORY_SCOPE_AGENT)
                   < (unsigned)NIB) {
                __builtin_amdgcn_s_sleep(16);   // ~1024cyc between polls
            }
        }
        __syncthreads();

        // ---- load corrected S2^T via 8B coherent loads (hbuf dead; aliased) ----
        {
            const unsigned long long* s2u = (const unsigned long long*)
                (S2T_g + ((size_t)cur * NB + b) * (NN * NN));
            for (int e = tid; e < (NN * NN) / 2; e += 512) {
                unsigned long long w = __hip_atomic_load(&s2u[e], __ATOMIC_RELAXED,
                                                         __HIP_MEMORY_SCOPE_AGENT);
                float2 f = *(float2*)&w;
                const int e0 = e * 2;
                S2T[e0 >> 5][e0 & 31] = f.x;
                S2T[e0 >> 5][(e0 & 31) + 1] = f.y;
            }
        }
        __syncthreads();

        // ---- phiB <- phase(E_t) * (S2' @ phiB): 32 rows x 16 lanes ----
        {
            const int ii = tid >> 4, l = tid & 15;
            double are = 0.0, aim = 0.0;
            #pragma unroll
            for (int jj = l; jj < NN; jj += 16) {
                double sv = (double)S2T[jj][ii];
                are += sv * phre[jj]; aim += sv * phim[jj];
            }
            are += __shfl_xor(are, 1); aim += __shfl_xor(aim, 1);
            are += __shfl_xor(are, 2); aim += __shfl_xor(aim, 2);
            are += __shfl_xor(are, 4); aim += __shfl_xor(aim, 4);
            are += __shfl_xor(are, 8); aim += __shfl_xor(aim, 8);
            if (l == 0) {
                double th = (double)EL[cur][ii] * (TWO_PI * ICM2IFS) * dtb;   // |th| < ~0.1
                double x2 = th * th;        // poly sincos, |err| ~1e-16 at this range
                double sph = th * (1.0 + x2 * (-1.0 / 6.0 + x2 * (1.0 / 120.0 + x2 * (-1.0 / 5040.0 + x2 * (1.0 / 362880.0)))));
                double cph = 1.0 + x2 * (-0.5 + x2 * (1.0 / 24.0 + x2 * (-1.0 / 720.0 + x2 * (1.0 / 40320.0))));
                double nre = cph * are + sph * aim;            // exp(-iEw) = c - i s
                double nim = cph * aim - sph * are;
                nreS[ii] = nre; nimS[ii] = nim;
                redl[ii] = nre * nre + nim * nim;
            }
        }
        __syncthreads();

        // ---- normalize (32-lane butterfly), update carry + phi2 ----
        if (tid < NN) {
            double v = redl[tid];
            v += __shfl_xor(v, 1); v += __shfl_xor(v, 2); v += __shfl_xor(v, 4);
            v += __shfl_xor(v, 8); v += __shfl_xor(v, 16);
            double sc = 1.0 / sqrt(v);
            double nr = nreS[tid] * sc, ni = nimS[tid] * sc;
            phre[tid] = nr; phim[tid] = ni;
            phi2l[tid] = (float)(nr * nr + ni * ni);
        }
        __syncthreads();

        // ---- ploc (every NSI steps, 2 rows per sibling) + ratio finalize ----
        if ((t % NSI) == 0 && tid < 32) {
            const int ii = iblk * 2 + (tid >> 4), l = tid & 15;
            double are = 0.0, aim = 0.0;
            #pragma unroll
            for (int jj = l; jj < NN; jj += 16) {
                double cij = (double)CpN[cur][jj][ii];   // C_t[i][j] = CT_t[j][i]
                are += cij * phre[jj]; aim += cij * phim[jj];
            }
            are += __shfl_xor(are, 1); aim += __shfl_xor(aim, 1);
            are += __shfl_xor(are, 2); aim += __shfl_xor(aim, 2);
            are += __shfl_xor(are, 4); aim += __shfl_xor(aim, 4);
            are += __shfl_xor(are, 8); aim += __shfl_xor(aim, 8);
            if (l == 0)
                out[((size_t)b * 61 + t / NSI) * NN + ii] = (float)(are * are + aim * aim);
        }
        if (t < NSTEPS && tid < 64) {      // ratio for t+1 (needs fresh phi2l)
            const int i = tid & 31, j = j0 + (tid >> 5);
            const float p_i = phi2l[i], p_j = phi2l[j];
            featS[tid].y = (p_j > 0.01f * p_i) ? (p_i / p_j) : 100.f;
        }
    }
}

// ---------------------------------------------------------------------------
extern "C" void kernel_launch(void* const* d_in, const int* in_sizes, int n_in,
                              void* d_out, int out_size, void* d_ws, size_t ws_size,
                              hipStream_t stream)
{
    const float* Tarr = (const float*)d_in[0];
    const float* ErA  = (const float*)d_in[1];
    const float* ctA  = (const float*)d_in[2];
    const float* dtA  = (const float*)d_in[4];
    const float* psi0 = (const float*)d_in[6];
    const float* Hf   = (const float*)d_in[7];
    const float* W1   = (const float*)d_in[8];
    const float* b1   = (const float*)d_in[9];
    const float* W2   = (const float*)d_in[10];
    const float* b2   = (const float*)d_in[11];
    const float* W3   = (const float*)d_in[12];
    const float* b3   = (const float*)d_in[13];
    const float* W4   = (const float*)d_in[14];
    const float* b4   = (const float*)d_in[15];

    unsigned int* cnt = (unsigned int*)d_ws;                    // 32*600 counters
    float* E_all  = (float*)(cnt + (size_t)NB * NSTEPS);        // 32*601*32
    float* CT_all = E_all + (size_t)NB * NT1 * NN;              // 32*601*32*32
    float* W2p    = CT_all + (size_t)NB * NT1 * NN * NN;        // 7680
    float* W3p    = W2p + 8 * NKB * 48;                         // 7680
    float4* L1W4  = (float4*)(W3p + 8 * NKB * 48);              // 80 f4
    float4* L1B4  = L1W4 + NU;                                  // 80 f4
    float* bpad   = (float*)(L1B4 + NU);                        // 3*80
    float* S2T_g  = bpad + 3 * NU;                              // 2*32*32*32
    int*   kk_all = (int*)(S2T_g + 2 * (size_t)NB * NN * NN);   // 32*600*32
    float* outp   = (float*)d_out;

    hipMemsetAsync(cnt, 0, (size_t)NB * NSTEPS * sizeof(unsigned int), stream);
    eigh_kernel<<<NB * NT1, 64, 0, stream>>>(Hf, E_all, CT_all);
    wtrans_kernel<<<1, 256, 0, stream>>>(W1, b1, W2, W3, b2, b3, W4,
                                         W2p, W3p, L1W4, L1B4, bpad);
    kk_kernel<<<NB * NSTEPS, 256, 0, stream>>>(CT_all, kk_all);

    // dyn LDS: two f4 tables (80 each) + 4x80 biases + hbuf 80*64
    const size_t dynf = (size_t)(8 * NU) + 4 * NU + NU * 64;
    persist_kernel<<<NB * NIB, 512, dynf * sizeof(float), stream>>>(E_all, CT_all,
        kk_all, psi0, Tarr, ErA, ctA, dtA, W2p, W3p, L1W4, L1B4, bpad, b4,
        S2T_g, cnt, outp);
}

// Round 4
// 46732.352 us; speedup vs baseline: 2.8045x; 2.8045x over previous
//
#include <hip/hip_runtime.h>
#include <math.h>

#define NB 32
#define NN 32
#define NSTEPS 600
#define NT1 601
#define NSI 10
#define NH 75
#define NU 80      // padded u (8 groups x 10)
#define NKB 20     // padded k-blocks of 4 (k padded 75 -> 80)
#define NIB 16     // sibling blocks per batch element

#define ICM2IFS 2.99792458e-05
#define KBOLTZ 0.6950389f
#define TWO_PI 6.283185307179586476925286766559

__device__ __forceinline__ float elu1(float x) { return x > 0.f ? x : (__expf(x) - 1.f); }

// ---------------------------------------------------------------------------
// Phase A: batched 32x32 symmetric eigensolver (parallel cyclic Jacobi).
// Unchanged.
// ---------------------------------------------------------------------------
__global__ __launch_bounds__(64) void eigh_kernel(const float* __restrict__ Hf,
                                                  float* __restrict__ E_all,
                                                  float* __restrict__ CT_all)
{
    __shared__ double A[NN][NN + 1];
    __shared__ float  V[NN][NN + 1];
    __shared__ double csC[16], csS[16];
    __shared__ int   prC[16], qrC[16];
    __shared__ double redv;
    __shared__ int   rankl[NN];

    const int idx = blockIdx.x;      // b*601 + t
    const int tid = threadIdx.x;
    const float* Hp = Hf + (size_t)idx * (NN * NN);

    for (int e = tid; e < NN * NN; e += 64) {
        A[e >> 5][e & 31] = (double)Hp[e];
        V[e >> 5][e & 31] = ((e >> 5) == (e & 31)) ? 1.f : 0.f;
    }
    __syncthreads();

    double part = 0.0;
    for (int e = tid; e < NN * NN; e += 64) { double v = A[e >> 5][e & 31]; part += v * v; }
    #pragma unroll
    for (int off = 32; off > 0; off >>= 1) part += __shfl_down(part, off);
    if (tid == 0) redv = part;
    __syncthreads();
    const double tol2 = 1e-20 * redv;

    for (int sweep = 0; sweep < 10; ++sweep) {
        for (int r = 0; r < NN - 1; ++r) {
            if (tid < 16) {
                int m = tid, p, q;
                if (m == 0) { p = 0; q = 1 + (r % 31); }
                else { p = 1 + ((m + r) % 31); q = 1 + ((31 - m + r) % 31); }
                double apq = A[p][q];
                double c = 1.0, sn = 0.0;
                if (apq != 0.0) {
                    double theta = 0.5 * (A[q][q] - A[p][p]) / apq;
                    double tt = 1.0 / (fabs(theta) + sqrt(theta * theta + 1.0));
                    if (theta < 0.0) tt = -tt;
                    c = 1.0 / sqrt(tt * tt + 1.0);
                    sn = tt * c;
                }
                csC[m] = c; csS[m] = sn; prC[m] = p; qrC[m] = q;
            }
            __syncthreads();
            #pragma unroll
            for (int it = 0; it < 8; ++it) {          // rows: A <- J^T A
                int task = tid + it * 64;
                int m = task >> 5, jc = task & 31;
                int p = prC[m], q = qrC[m];
                double c = csC[m], sn = csS[m];
                double ap = A[p][jc], aq = A[q][jc];
                A[p][jc] = c * ap - sn * aq;
                A[q][jc] = sn * ap + c * aq;
            }
            __syncthreads();
            #pragma unroll
            for (int it = 0; it < 16; ++it) {         // cols: A <- A J (f64), V <- V J (f32)
                int task = tid + it * 64;
                int m = (task >> 5) & 15, ir = task & 31;
                int p = prC[m], q = qrC[m];
                if (task < 512) {
                    double c = csC[m], sn = csS[m];
                    double aip = A[ir][p], aiq = A[ir][q];
                    A[ir][p] = c * aip - sn * aiq;
                    A[ir][q] = sn * aip + c * aiq;
                } else {
                    float cf = (float)csC[m], sf = (float)csS[m];
                    float vip = V[ir][p], viq = V[ir][q];
                    V[ir][p] = cf * vip - sf * viq;
                    V[ir][q] = sf * vip + cf * viq;
                }
            }
            __syncthreads();
        }
        if (sweep >= 3) {
            double o = 0.0;
            for (int e = tid; e < NN * NN; e += 64) {
                int i2 = e >> 5, j2 = e & 31;
                double v = A[i2][j2];
                o += (i2 != j2) ? v * v : 0.0;
            }
            #pragma unroll
            for (int off = 32; off > 0; off >>= 1) o += __shfl_down(o, off);
            if (tid == 0) redv = o;
            __syncthreads();
            if (redv <= tol2) break;
        }
    }
    __syncthreads();

    if (tid < NN) {
        double ei = A[tid][tid];
        int rk = 0;
        for (int j2 = 0; j2 < NN; ++j2) {
            double ej = A[j2][j2];
            rk += (ej < ei || (ej == ei && j2 < tid)) ? 1 : 0;
        }
        rankl[tid] = rk;
        E_all[(size_t)idx * NN + rk] = (float)ei;
    }
    __syncthreads();
    float* ct = CT_all + (size_t)idx * NN * NN;
    for (int e = tid; e < NN * NN; e += 64) {
        int col = e >> 5, m2 = e & 31;
        ct[(size_t)rankl[col] * NN + m2] = V[m2][col];
    }
}

// ---------------------------------------------------------------------------
// Phase A2: kk[b,s,j] = argmax_i S[b,s,i,j]^2 (first index on ties)
// ---------------------------------------------------------------------------
__global__ __launch_bounds__(256) void kk_kernel(const float* __restrict__ CT_all,
                                                 int* __restrict__ kk_all)
{
    __shared__ float Ct[NN][NN + 1], Cp[NN][NN + 1], S[NN][NN + 1];
    const int blk = blockIdx.x;                // b*600 + (s-1)
    const int b = blk / NSTEPS, s = blk % NSTEPS + 1;
    const int tid = threadIdx.x;
    const float* ctg = CT_all + ((size_t)b * NT1 + s) * (NN * NN);
    const float* cpg = CT_all + ((size_t)b * NT1 + s - 1) * (NN * NN);
    for (int e = tid; e < NN * NN; e += 256) {
        Ct[e >> 5][e & 31] = ctg[e];
        Cp[e >> 5][e & 31] = cpg[e];
    }
    __syncthreads();
    for (int e = tid; e < NN * NN; e += 256) {
        int i = e >> 5, j = e & 31;
        float acc = 0.f;
        for (int m = 0; m < NN; ++m) acc += Ct[i][m] * Cp[j][m];
        S[i][j] = acc;
    }
    __syncthreads();
    if (tid < NN) {
        const int j = tid;
        float best = -1.f; int bi = 0;
        for (int i = 0; i < NN; ++i) {
            float v = S[i][j]; v *= v;
            if (v > best) { best = v; bi = i; }
        }
        kk_all[(size_t)blk * NN + j] = bi;
    }
}

// ---------------------------------------------------------------------------
// Pack weights: Wp[ug 8][kb 20][kp 4][12] (10 u + 2 pad, 16B rows; zero pad).
// ---------------------------------------------------------------------------
__global__ void wtrans_kernel(const float* __restrict__ W1, const float* __restrict__ b1,
                              const float* __restrict__ W2, const float* __restrict__ W3,
                              const float* __restrict__ b2, const float* __restrict__ b3,
                              const float* __restrict__ W4,
                              float* __restrict__ W2p, float* __restrict__ W3p,
                              float4* __restrict__ L1W4, float4* __restrict__ L1B4,
                              float* __restrict__ bpad)
{
    const int tid = threadIdx.x;
    const int tot = 8 * NKB * 4 * 12;          // 7680
    for (int e = tid; e < tot; e += 256) {
        int ug = e / (NKB * 4 * 12);
        int kb = (e / (4 * 12)) % NKB;
        int kp = (e / 12) & 3;
        int uu = e % 12;
        int u = ug * 10 + uu;
        int k = kb * 4 + kp;
        float v2 = 0.f, v3 = 0.f;
        if (uu < 10 && u < NH && k < NH) {
            v2 = W2[u * NH + k];
            v3 = W3[u * NH + k];
        }
        W2p[e] = v2; W3p[e] = v3;
    }
    if (tid < NU) {
        if (tid < NH) {
            const float* w = W1 + tid * 8;
            L1W4[tid] = make_float4(w[0], w[1], w[2], w[7]);
            L1B4[tid] = make_float4(w[3], w[4], w[5], b1[tid]);
            bpad[tid]          = b2[tid];
            bpad[NU + tid]     = b3[tid];
            bpad[2 * NU + tid] = W4[tid];
        } else {
            L1W4[tid] = make_float4(0.f, 0.f, 0.f, 0.f);
            L1B4[tid] = make_float4(0.f, 0.f, 0.f, 0.f);
            bpad[tid] = 0.f; bpad[NU + tid] = 0.f; bpad[2 * NU + tid] = 0.f;
        }
    }
}

// ---------------------------------------------------------------------------
// Phase B persistent kernel. R14 = R13 structure with the REAL R12/R13
// regression fixed:
//   * R12/R13 root cause was NOT the spin poll (R13 cut poll rate 10x,
//     counters identical). It was __launch_bounds__(512, 4): VGPR cap 64
//     -> the kb-loop working set spilled to scratch. ~640B/thread/step of
//     spill+fill x 512thr x 512blk x 600steps = ~200 GB each way == the
//     measured FETCH 195 GB / WRITE 203 GB (symmetric, timing-invariant).
//   * Fix: restore __launch_bounds__(512, 2) (R1-proven, VGPR ~80 -> no
//     spill; 80 VGPR = 6 waves/SIMD >= the 4 needed for 2 blocks/CU, and
//     LDS 38.6 KB x 2 fits) -> clean measurement of the 16-sibling
//     structure at 2 blocks/CU.
//   * Spin cadence s_sleep(4) (~256cyc): poll traffic trivial, exit
//     latency ~0.1us.
// ---------------------------------------------------------------------------
__global__ __launch_bounds__(512, 2) void persist_kernel(
    const float* __restrict__ E_all, const float* __restrict__ CT_all,
    const int* __restrict__ kk_all, const float* __restrict__ psi0,
    const float* __restrict__ Tarr, const float* __restrict__ ErA,
    const float* __restrict__ ctA, const float* __restrict__ dtA,
    const float* __restrict__ W2p, const float* __restrict__ W3p,
    const float4* __restrict__ L1W4g, const float4* __restrict__ L1B4g,
    const float* __restrict__ bpad, const float* __restrict__ b4v,
    float* __restrict__ S2T_g, unsigned int* __restrict__ cnt,
    float* __restrict__ out)
{
    extern __shared__ __align__(16) float dyn[];
    float4* L1Wl = (float4*)dyn;                // 80 f4
    float4* L1Bl = L1Wl + NU;                   // 80 f4
    float* cst  = (float*)(L1Bl + NU);          // 80
    float* b2l  = cst + NU;                     // 80
    float* b3l  = b2l + NU;                     // 80
    float* W4l  = b3l + NU;                     // 80
    float* hbuf = W4l + NU;                     // 80*64 = 5120 floats
    float (*S2T)[NN + 4] = (float(*)[NN + 4])hbuf;   // aliases hbuf (disjoint lifetime)

    __shared__ float CpN[2][NN][NN + 4];
    __shared__ float4 featS[64];                // {DE, ratio, Sv, ex} per pair
    __shared__ float a4b2[8][64];
    __shared__ float EL[2][NN];
    __shared__ int   kkL[2][NN];
    __shared__ double phre[NN], phim[NN], redl[NN], nreS[NN], nimS[NN];
    __shared__ float phi2l[NN];

    const int tid  = threadIdx.x;
    const int b    = blockIdx.x >> 4;           // sibling sets are CONSECUTIVE idx
    const int iblk = blockIdx.x & 15;
    const int j0   = iblk * 2;                  // owns columns j0, j0+1
    const int ug   = __builtin_amdgcn_readfirstlane(tid >> 6);  // uniform wave id
    const int rg   = tid & 63;                  // pair index r: i = r&31, j = j0+(r>>5)
    const int U    = ug * 10;

    const float kbt = KBOLTZ * Tarr[b];
    const float er  = ErA[b];
    const float cti = ctA[b];
    const double dtb = (double)dtA[b];
    const float b4s = b4v[0];

    const float4* W2g = (const float4*)(W2p + (size_t)ug * (NKB * 48));
    const float4* W3g = (const float4*)(W3p + (size_t)ug * (NKB * 48));

    // ---- stage small loop-invariant tables into LDS (once) ----
    if (tid < NU) {
        L1Wl[tid] = L1W4g[tid];
        L1Bl[tid] = L1B4g[tid];
        b2l[tid] = bpad[tid];
        b3l[tid] = bpad[NU + tid];
        W4l[tid] = bpad[2 * NU + tid];
    }
    __syncthreads();
    if (tid < NU) {     // per-b constant part of layer-1 preactivation
        float4 lb = L1Bl[tid];
        cst[tid] = lb.w + lb.x * kbt + lb.y * er + lb.z * cti;
    }

    // ---- prime: C_0, C_1, E[0], E[1], kk[0]; init phiB; featS for s=1 ----
    {
        const float* c0g = CT_all + (size_t)b * NT1 * NN * NN;
        const float* c1g = c0g + NN * NN;
        for (int e = tid; e < NN * NN; e += 512) {
            CpN[0][e >> 5][e & 31] = c0g[e];
            CpN[1][e >> 5][e & 31] = c1g[e];
        }
        if (tid < NN) {
            EL[0][tid] = E_all[((size_t)b * NT1 + 0) * NN + tid];
            EL[1][tid] = E_all[((size_t)b * NT1 + 1) * NN + tid];
            kkL[1][tid] = kk_all[(size_t)b * NSTEPS * NN + tid];
        }
        __syncthreads();
        if (tid < NN) {
            const int i = tid;
            double acc = 0.0;
            for (int j = 0; j < NN; ++j) acc += (double)CpN[0][i][j] * (double)psi0[b * NN + j];
            phre[i] = acc; phim[i] = 0.0;
            phi2l[i] = (float)(acc * acc);
            if (iblk == 0) {
                float p0 = psi0[b * NN + i];
                out[((size_t)b * 61) * NN + i] = p0 * p0;
            }
        }
        __syncthreads();
        {   // features for step 1 (curS = 1): Sv/DE/ex, 8 lanes per pair
            const int r = tid >> 3, c = tid & 7;
            const int i = r & 31, j = j0 + (r >> 5);
            float Sv = 0.f;
            #pragma unroll
            for (int m = c; m < NN; m += 8)
                Sv += CpN[1][i][m] * CpN[0][j][m];
            Sv += __shfl_xor(Sv, 1); Sv += __shfl_xor(Sv, 2); Sv += __shfl_xor(Sv, 4);
            if (c == 0) {
                const int kj = kkL[1][j];
                const float DE = (i == kj) ? 0.f : (EL[1][i] - EL[0][j]);
                featS[r] = make_float4(DE, 100.f, Sv, __expf(DE / kbt));
            }
        }
        __syncthreads();
        if (tid < 64) {     // ratio for step 1
            const int i = tid & 31, j = j0 + (tid >> 5);
            const float p_i = phi2l[i], p_j = phi2l[j];
            featS[tid].y = (p_j > 0.01f * p_i) ? (p_i / p_j) : 100.f;
        }
    }

    for (int t = 1; t <= NSTEPS; ++t) {
        __syncthreads();                        // featS / phi2l visible
        const int cur = t & 1;

        // ---- issue prefetch loads for step t+1 (retire during MLP) ----
        float2 cpre = make_float2(0.f, 0.f);
        float  epre = 0.f;
        int    kpre = 0;
        if (t < NSTEPS) {
            const float* c1g = CT_all + ((size_t)b * NT1 + t + 1) * (NN * NN);
            cpre = ((const float2*)c1g)[tid];
            if (tid < NN) epre = E_all[((size_t)b * NT1 + t + 1) * NN + tid];
            else if (tid < 2 * NN) kpre = kk_all[((size_t)b * NSTEPS + t) * NN + (tid - NN)];
        }

        // ---- layer 1 (features -> h1), tile 10u x 1r ----
        {
            float4 f0 = featS[rg];
            #pragma unroll
            for (int u = 0; u < 10; ++u) {
                float4 wv = L1Wl[U + u];
                float c = cst[U + u];
                hbuf[(U + u) * 64 + rg] =
                    elu1(c + wv.x * f0.x + wv.y * f0.y + wv.z * f0.z + wv.w * f0.w);
            }
        }
        __syncthreads();

        // ---- layer 2 (h1 -> h2): weights via wave-uniform scalar loads ----
        float acc[10];
        #pragma unroll
        for (int u = 0; u < 10; ++u) acc[u] = b2l[U + u];
        for (int kb = 0; kb < NKB; ++kb) {
            float4 wv[12];
            float hv[4];
            #pragma unroll
            for (int m = 0; m < 12; ++m) wv[m] = W2g[kb * 12 + m];   // uniform -> s_load
            #pragma unroll
            for (int kk = 0; kk < 4; ++kk)
                hv[kk] = hbuf[(kb * 4 + kk) * 64 + rg];
            #pragma unroll
            for (int kk = 0; kk < 4; ++kk) {
                const float* wf = (const float*)&wv[kk * 3];
                #pragma unroll
                for (int u = 0; u < 10; ++u) acc[u] += wf[u] * hv[kk];
            }
        }
        __syncthreads();    // all reads of h1 done before overwriting hbuf
        #pragma unroll
        for (int u = 0; u < 10; ++u) hbuf[(U + u) * 64 + rg] = elu1(acc[u]);
        __syncthreads();

        // ---- layer 3 (h2 -> h3 in registers) ----
        #pragma unroll
        for (int u = 0; u < 10; ++u) acc[u] = b3l[U + u];
        for (int kb = 0; kb < NKB; ++kb) {
            float4 wv[12];
            float hv[4];
            #pragma unroll
            for (int m = 0; m < 12; ++m) wv[m] = W3g[kb * 12 + m];   // uniform -> s_load
            #pragma unroll
            for (int kk = 0; kk < 4; ++kk)
                hv[kk] = hbuf[(kb * 4 + kk) * 64 + rg];
            #pragma unroll
            for (int kk = 0; kk < 4; ++kk) {
                const float* wf = (const float*)&wv[kk * 3];
                #pragma unroll
                for (int u = 0; u < 10; ++u) acc[u] += wf[u] * hv[kk];
            }
        }
        // ---- layer 4 partials ----
        {
            float p4 = 0.f;
            #pragma unroll
            for (int u = 0; u < 10; ++u) p4 += W4l[U + u] * elu1(acc[u]);
            a4b2[ug][rg] = p4;
        }
        __syncthreads();

        // ---- finalize corr, IN-REGISTER column correction, coherent store,
        //      and EARLY arrival signal (all inside wave 0) ----
        if (tid < 64) {
            const int r = tid;
            const int i = r & 31;
            const int j = j0 + (r >> 5);
            float a4 = b4s;
            #pragma unroll
            for (int g = 0; g < 8; ++g) a4 += a4b2[g][r];
            const float corr = elu1(a4) + 1.f;
            float s2v = featS[r].z * corr;
            const int kj = kkL[cur][j];
            double v = (double)s2v;
            double cd = (i == kj) ? 0.0 : v * v;
            cd += __shfl_xor(cd, 1);  cd += __shfl_xor(cd, 2);
            cd += __shfl_xor(cd, 4);  cd += __shfl_xor(cd, 8);
            cd += __shfl_xor(cd, 16);
            if (i == kj) {
                double nrm = fabs(v); nrm = (nrm > 0.0) ? nrm : 1.0;
                double rem = 1.0 - cd;
                s2v = (float)((rem > 0.0) ? (sqrt(rem) * v / nrm) : v);
            }
            __hip_atomic_store(&S2T_g[(((size_t)cur * NB + b) * NN + j) * NN + i],
                               s2v, __ATOMIC_RELAXED, __HIP_MEMORY_SCOPE_AGENT);
            asm volatile("s_waitcnt vmcnt(0)" ::: "memory");    // drain coherent stores
            if (tid == 0)       // wave 0 stored everything -> signal NOW
                __hip_atomic_fetch_add(cnt + (size_t)b * NSTEPS + (t - 1), 1u,
                                       __ATOMIC_RELAXED, __HIP_MEMORY_SCOPE_AGENT);
        }

        // ---- commit prefetch into dead ping-pong slots (no sync needed:
        //      writes [1-cur] slots, wave 0 above reads only [cur]) ----
        if (t < NSTEPS) {
            const int e0 = tid * 2;
            CpN[1 - cur][e0 >> 5][e0 & 31] = cpre.x;
            CpN[1 - cur][e0 >> 5][(e0 & 31) + 1] = cpre.y;
            if (tid < NN) EL[1 - cur][tid] = epre;
            else if (tid < 2 * NN) kkL[1 - cur][tid - NN] = kpre;
        }
        __syncthreads();

        // ---- features for t+1 (Sv/DE/ex) — hidden inside the spin window ----
        if (t < NSTEPS) {
            const int curS = 1 - cur;
            const int r = tid >> 3, c = tid & 7;
            const int i = r & 31, j = j0 + (r >> 5);
            float Sv = 0.f;
            #pragma unroll
            for (int m = c; m < NN; m += 8)
                Sv += CpN[curS][i][m] * CpN[1 - curS][j][m];
            Sv += __shfl_xor(Sv, 1); Sv += __shfl_xor(Sv, 2); Sv += __shfl_xor(Sv, 4);
            if (c == 0) {
                const int kj = kkL[curS][j];
                const float DE = (i == kj) ? 0.f : (EL[curS][i] - EL[1 - curS][j]);
                featS[r] = make_float4(DE, 100.f, Sv, __expf(DE / kbt));
            }
        }

        // ---- sibling barrier: poll + sleep-backoff ----
        if (tid == 0) {
            const unsigned int* c = cnt + (size_t)b * NSTEPS + (t - 1);
            while (__hip_atomic_load(c, __ATOMIC_RELAXED, __HIP_MEMORY_SCOPE_AGENT)
                   < (unsigned)NIB) {
                __builtin_amdgcn_s_sleep(4);    // ~256cyc between polls
            }
        }
        __syncthreads();

        // ---- load corrected S2^T via 8B coherent loads (hbuf dead; aliased) ----
        {
            const unsigned long long* s2u = (const unsigned long long*)
                (S2T_g + ((size_t)cur * NB + b) * (NN * NN));
            for (int e = tid; e < (NN * NN) / 2; e += 512) {
                unsigned long long w = __hip_atomic_load(&s2u[e], __ATOMIC_RELAXED,
                                                         __HIP_MEMORY_SCOPE_AGENT);
                float2 f = *(float2*)&w;
                const int e0 = e * 2;
                S2T[e0 >> 5][e0 & 31] = f.x;
                S2T[e0 >> 5][(e0 & 31) + 1] = f.y;
            }
        }
        __syncthreads();

        // ---- phiB <- phase(E_t) * (S2' @ phiB): 32 rows x 16 lanes ----
        {
            const int ii = tid >> 4, l = tid & 15;
            double are = 0.0, aim = 0.0;
            #pragma unroll
            for (int jj = l; jj < NN; jj += 16) {
                double sv = (double)S2T[jj][ii];
                are += sv * phre[jj]; aim += sv * phim[jj];
            }
            are += __shfl_xor(are, 1); aim += __shfl_xor(aim, 1);
            are += __shfl_xor(are, 2); aim += __shfl_xor(aim, 2);
            are += __shfl_xor(are, 4); aim += __shfl_xor(aim, 4);
            are += __shfl_xor(are, 8); aim += __shfl_xor(aim, 8);
            if (l == 0) {
                double th = (double)EL[cur][ii] * (TWO_PI * ICM2IFS) * dtb;   // |th| < ~0.1
                double x2 = th * th;        // poly sincos, |err| ~1e-16 at this range
                double sph = th * (1.0 + x2 * (-1.0 / 6.0 + x2 * (1.0 / 120.0 + x2 * (-1.0 / 5040.0 + x2 * (1.0 / 362880.0)))));
                double cph = 1.0 + x2 * (-0.5 + x2 * (1.0 / 24.0 + x2 * (-1.0 / 720.0 + x2 * (1.0 / 40320.0))));
                double nre = cph * are + sph * aim;            // exp(-iEw) = c - i s
                double nim = cph * aim - sph * are;
                nreS[ii] = nre; nimS[ii] = nim;
                redl[ii] = nre * nre + nim * nim;
            }
        }
        __syncthreads();

        // ---- normalize (32-lane butterfly), update carry + phi2 ----
        if (tid < NN) {
            double v = redl[tid];
            v += __shfl_xor(v, 1); v += __shfl_xor(v, 2); v += __shfl_xor(v, 4);
            v += __shfl_xor(v, 8); v += __shfl_xor(v, 16);
            double sc = 1.0 / sqrt(v);
            double nr = nreS[tid] * sc, ni = nimS[tid] * sc;
            phre[tid] = nr; phim[tid] = ni;
            phi2l[tid] = (float)(nr * nr + ni * ni);
        }
        __syncthreads();

        // ---- ploc (every NSI steps, 2 rows per sibling) + ratio finalize ----
        if ((t % NSI) == 0 && tid < 32) {
            const int ii = iblk * 2 + (tid >> 4), l = tid & 15;
            double are = 0.0, aim = 0.0;
            #pragma unroll
            for (int jj = l; jj < NN; jj += 16) {
                double cij = (double)CpN[cur][jj][ii];   // C_t[i][j] = CT_t[j][i]
                are += cij * phre[jj]; aim += cij * phim[jj];
            }
            are += __shfl_xor(are, 1); aim += __shfl_xor(aim, 1);
            are += __shfl_xor(are, 2); aim += __shfl_xor(aim, 2);
            are += __shfl_xor(are, 4); aim += __shfl_xor(aim, 4);
            are += __shfl_xor(are, 8); aim += __shfl_xor(aim, 8);
            if (l == 0)
                out[((size_t)b * 61 + t / NSI) * NN + ii] = (float)(are * are + aim * aim);
        }
        if (t < NSTEPS && tid < 64) {      // ratio for t+1 (needs fresh phi2l)
            const int i = tid & 31, j = j0 + (tid >> 5);
            const float p_i = phi2l[i], p_j = phi2l[j];
            featS[tid].y = (p_j > 0.01f * p_i) ? (p_i / p_j) : 100.f;
        }
    }
}

// ---------------------------------------------------------------------------
extern "C" void kernel_launch(void* const* d_in, const int* in_sizes, int n_in,
                              void* d_out, int out_size, void* d_ws, size_t ws_size,
                              hipStream_t stream)
{
    const float* Tarr = (const float*)d_in[0];
    const float* ErA  = (const float*)d_in[1];
    const float* ctA  = (const float*)d_in[2];
    const float* dtA  = (const float*)d_in[4];
    const float* psi0 = (const float*)d_in[6];
    const float* Hf   = (const float*)d_in[7];
    const float* W1   = (const float*)d_in[8];
    const float* b1   = (const float*)d_in[9];
    const float* W2   = (const float*)d_in[10];
    const float* b2   = (const float*)d_in[11];
    const float* W3   = (const float*)d_in[12];
    const float* b3   = (const float*)d_in[13];
    const float* W4   = (const float*)d_in[14];
    const float* b4   = (const float*)d_in[15];

    unsigned int* cnt = (unsigned int*)d_ws;                    // 32*600 counters
    float* E_all  = (float*)(cnt + (size_t)NB * NSTEPS);        // 32*601*32
    float* CT_all = E_all + (size_t)NB * NT1 * NN;              // 32*601*32*32
    float* W2p    = CT_all + (size_t)NB * NT1 * NN * NN;        // 7680
    float* W3p    = W2p + 8 * NKB * 48;                         // 7680
    float4* L1W4  = (float4*)(W3p + 8 * NKB * 48);              // 80 f4
    float4* L1B4  = L1W4 + NU;                                  // 80 f4
    float* bpad   = (float*)(L1B4 + NU);                        // 3*80
    float* S2T_g  = bpad + 3 * NU;                              // 2*32*32*32
    int*   kk_all = (int*)(S2T_g + 2 * (size_t)NB * NN * NN);   // 32*600*32
    float* outp   = (float*)d_out;

    hipMemsetAsync(cnt, 0, (size_t)NB * NSTEPS * sizeof(unsigned int), stream);
    eigh_kernel<<<NB * NT1, 64, 0, stream>>>(Hf, E_all, CT_all);
    wtrans_kernel<<<1, 256, 0, stream>>>(W1, b1, W2, W3, b2, b3, W4,
                                         W2p, W3p, L1W4, L1B4, bpad);
    kk_kernel<<<NB * NSTEPS, 256, 0, stream>>>(CT_all, kk_all);

    // dyn LDS: two f4 tables (80 each) + 4x80 biases + hbuf 80*64
    const size_t dynf = (size_t)(8 * NU) + 4 * NU + NU * 64;
    persist_kernel<<<NB * NIB, 512, dynf * sizeof(float), stream>>>(E_all, CT_all,
        kk_all, psi0, Tarr, ErA, ctA, dtA, W2p, W3p, L1W4, L1B4, bpad, b4,
        S2T_g, cnt, outp);
}

// Round 5
// 14646.712 us; speedup vs baseline: 8.9482x; 3.1906x over previous
//
#include <hip/hip_runtime.h>
#include <math.h>

#define NB 32
#define NN 32
#define NSTEPS 600
#define NT1 601
#define NSI 10
#define NH 75
#define NU 80      // padded u (8 groups x 10)
#define NKB 20     // padded k-blocks of 4 (k padded 75 -> 80)
#define NIB 8      // sibling blocks per batch element (R1-proven; grid = 256 = #CUs)

#define ICM2IFS 2.99792458e-05
#define KBOLTZ 0.6950389f
#define TWO_PI 6.283185307179586476925286766559

__device__ __forceinline__ float elu1(float x) { return x > 0.f ? x : (__expf(x) - 1.f); }

// ---------------------------------------------------------------------------
// Phase A: batched 32x32 symmetric eigensolver (parallel cyclic Jacobi).
// Unchanged.
// ---------------------------------------------------------------------------
__global__ __launch_bounds__(64) void eigh_kernel(const float* __restrict__ Hf,
                                                  float* __restrict__ E_all,
                                                  float* __restrict__ CT_all)
{
    __shared__ double A[NN][NN + 1];
    __shared__ float  V[NN][NN + 1];
    __shared__ double csC[16], csS[16];
    __shared__ int   prC[16], qrC[16];
    __shared__ double redv;
    __shared__ int   rankl[NN];

    const int idx = blockIdx.x;      // b*601 + t
    const int tid = threadIdx.x;
    const float* Hp = Hf + (size_t)idx * (NN * NN);

    for (int e = tid; e < NN * NN; e += 64) {
        A[e >> 5][e & 31] = (double)Hp[e];
        V[e >> 5][e & 31] = ((e >> 5) == (e & 31)) ? 1.f : 0.f;
    }
    __syncthreads();

    double part = 0.0;
    for (int e = tid; e < NN * NN; e += 64) { double v = A[e >> 5][e & 31]; part += v * v; }
    #pragma unroll
    for (int off = 32; off > 0; off >>= 1) part += __shfl_down(part, off);
    if (tid == 0) redv = part;
    __syncthreads();
    const double tol2 = 1e-20 * redv;

    for (int sweep = 0; sweep < 10; ++sweep) {
        for (int r = 0; r < NN - 1; ++r) {
            if (tid < 16) {
                int m = tid, p, q;
                if (m == 0) { p = 0; q = 1 + (r % 31); }
                else { p = 1 + ((m + r) % 31); q = 1 + ((31 - m + r) % 31); }
                double apq = A[p][q];
                double c = 1.0, sn = 0.0;
                if (apq != 0.0) {
                    double theta = 0.5 * (A[q][q] - A[p][p]) / apq;
                    double tt = 1.0 / (fabs(theta) + sqrt(theta * theta + 1.0));
                    if (theta < 0.0) tt = -tt;
                    c = 1.0 / sqrt(tt * tt + 1.0);
                    sn = tt * c;
                }
                csC[m] = c; csS[m] = sn; prC[m] = p; qrC[m] = q;
            }
            __syncthreads();
            #pragma unroll
            for (int it = 0; it < 8; ++it) {          // rows: A <- J^T A
                int task = tid + it * 64;
                int m = task >> 5, jc = task & 31;
                int p = prC[m], q = qrC[m];
                double c = csC[m], sn = csS[m];
                double ap = A[p][jc], aq = A[q][jc];
                A[p][jc] = c * ap - sn * aq;
                A[q][jc] = sn * ap + c * aq;
            }
            __syncthreads();
            #pragma unroll
            for (int it = 0; it < 16; ++it) {         // cols: A <- A J (f64), V <- V J (f32)
                int task = tid + it * 64;
                int m = (task >> 5) & 15, ir = task & 31;
                int p = prC[m], q = qrC[m];
                if (task < 512) {
                    double c = csC[m], sn = csS[m];
                    double aip = A[ir][p], aiq = A[ir][q];
                    A[ir][p] = c * aip - sn * aiq;
                    A[ir][q] = sn * aip + c * aiq;
                } else {
                    float cf = (float)csC[m], sf = (float)csS[m];
                    float vip = V[ir][p], viq = V[ir][q];
                    V[ir][p] = cf * vip - sf * viq;
                    V[ir][q] = sf * vip + cf * viq;
                }
            }
            __syncthreads();
        }
        if (sweep >= 3) {
            double o = 0.0;
            for (int e = tid; e < NN * NN; e += 64) {
                int i2 = e >> 5, j2 = e & 31;
                double v = A[i2][j2];
                o += (i2 != j2) ? v * v : 0.0;
            }
            #pragma unroll
            for (int off = 32; off > 0; off >>= 1) o += __shfl_down(o, off);
            if (tid == 0) redv = o;
            __syncthreads();
            if (redv <= tol2) break;
        }
    }
    __syncthreads();

    if (tid < NN) {
        double ei = A[tid][tid];
        int rk = 0;
        for (int j2 = 0; j2 < NN; ++j2) {
            double ej = A[j2][j2];
            rk += (ej < ei || (ej == ei && j2 < tid)) ? 1 : 0;
        }
        rankl[tid] = rk;
        E_all[(size_t)idx * NN + rk] = (float)ei;
    }
    __syncthreads();
    float* ct = CT_all + (size_t)idx * NN * NN;
    for (int e = tid; e < NN * NN; e += 64) {
        int col = e >> 5, m2 = e & 31;
        ct[(size_t)rankl[col] * NN + m2] = V[m2][col];
    }
}

// ---------------------------------------------------------------------------
// Phase A2: kk[b,s,j] = argmax_i S[b,s,i,j]^2 (first index on ties)
// ---------------------------------------------------------------------------
__global__ __launch_bounds__(256) void kk_kernel(const float* __restrict__ CT_all,
                                                 int* __restrict__ kk_all)
{
    __shared__ float Ct[NN][NN + 1], Cp[NN][NN + 1], S[NN][NN + 1];
    const int blk = blockIdx.x;                // b*600 + (s-1)
    const int b = blk / NSTEPS, s = blk % NSTEPS + 1;
    const int tid = threadIdx.x;
    const float* ctg = CT_all + ((size_t)b * NT1 + s) * (NN * NN);
    const float* cpg = CT_all + ((size_t)b * NT1 + s - 1) * (NN * NN);
    for (int e = tid; e < NN * NN; e += 256) {
        Ct[e >> 5][e & 31] = ctg[e];
        Cp[e >> 5][e & 31] = cpg[e];
    }
    __syncthreads();
    for (int e = tid; e < NN * NN; e += 256) {
        int i = e >> 5, j = e & 31;
        float acc = 0.f;
        for (int m = 0; m < NN; ++m) acc += Ct[i][m] * Cp[j][m];
        S[i][j] = acc;
    }
    __syncthreads();
    if (tid < NN) {
        const int j = tid;
        float best = -1.f; int bi = 0;
        for (int i = 0; i < NN; ++i) {
            float v = S[i][j]; v *= v;
            if (v > best) { best = v; bi = i; }
        }
        kk_all[(size_t)blk * NN + j] = bi;
    }
}

// ---------------------------------------------------------------------------
// Pack weights: Wp[ug 8][kb 20][kp 4][12] (10 u + 2 pad, 16B rows; zero pad).
// ---------------------------------------------------------------------------
__global__ void wtrans_kernel(const float* __restrict__ W1, const float* __restrict__ b1,
                              const float* __restrict__ W2, const float* __restrict__ W3,
                              const float* __restrict__ b2, const float* __restrict__ b3,
                              const float* __restrict__ W4,
                              float* __restrict__ W2p, float* __restrict__ W3p,
                              float4* __restrict__ L1W4, float4* __restrict__ L1B4,
                              float* __restrict__ bpad)
{
    const int tid = threadIdx.x;
    const int tot = 8 * NKB * 4 * 12;          // 7680
    for (int e = tid; e < tot; e += 256) {
        int ug = e / (NKB * 4 * 12);
        int kb = (e / (4 * 12)) % NKB;
        int kp = (e / 12) & 3;
        int uu = e % 12;
        int u = ug * 10 + uu;
        int k = kb * 4 + kp;
        float v2 = 0.f, v3 = 0.f;
        if (uu < 10 && u < NH && k < NH) {
            v2 = W2[u * NH + k];
            v3 = W3[u * NH + k];
        }
        W2p[e] = v2; W3p[e] = v3;
    }
    if (tid < NU) {
        if (tid < NH) {
            const float* w = W1 + tid * 8;
            L1W4[tid] = make_float4(w[0], w[1], w[2], w[7]);
            L1B4[tid] = make_float4(w[3], w[4], w[5], b1[tid]);
            bpad[tid]          = b2[tid];
            bpad[NU + tid]     = b3[tid];
            bpad[2 * NU + tid] = W4[tid];
        } else {
            L1W4[tid] = make_float4(0.f, 0.f, 0.f, 0.f);
            L1B4[tid] = make_float4(0.f, 0.f, 0.f, 0.f);
            bpad[tid] = 0.f; bpad[NU + tid] = 0.f; bpad[2 * NU + tid] = 0.f;
        }
    }
}

// ---------------------------------------------------------------------------
// Phase B persistent kernel, R15:
//   REVERT to R1 geometry (co-residency refuted by R2-R4: 64-VGPR cap ->
//   scratch spill; 128 VGPR -> HW still 1 block/CU and the 512-block grid
//   SERIALIZED into two halves = 4x regression). 256 blocks x 512 thr,
//   grid == #CUs, deterministic 1 block/CU, 8 siblings per b.
//   KEEP the co-residency-independent R2 wins, applied to column ownership
//   (j0 = iblk*4, 4 columns x 32 i = 128 cells/block):
//   * fp64 column-correction IN-REGISTER (32-lane shfl) before the store —
//     deletes one exchange phase + barrier from the critical path.
//   * fp64 tail parallel: phiB matvec 32 rows x 16 lanes (512 thr, was 32
//     serial), normalize 32-lane butterfly, ploc 4 rows/sibling.
//   * features for t+1 (Sv/DE/ex) computed INSIDE the sibling-spin window;
//     ratio finalized after normalize.
//   * per-wave early signal: each of the 2 storing waves signals after its
//     own vmcnt(0) drain (counter target 2*NIB = 16).
//   * slim LDS (~62 KB), s_sleep(4) spin, 8B coherent readback.
// ---------------------------------------------------------------------------
__global__ __launch_bounds__(512, 2) void persist_kernel(
    const float* __restrict__ E_all, const float* __restrict__ CT_all,
    const int* __restrict__ kk_all, const float* __restrict__ psi0,
    const float* __restrict__ Tarr, const float* __restrict__ ErA,
    const float* __restrict__ ctA, const float* __restrict__ dtA,
    const float* __restrict__ W2p, const float* __restrict__ W3p,
    const float4* __restrict__ L1W4g, const float4* __restrict__ L1B4g,
    const float* __restrict__ bpad, const float* __restrict__ b4v,
    float* __restrict__ S2T_g, unsigned int* __restrict__ cnt,
    float* __restrict__ out)
{
    extern __shared__ __align__(16) float dyn[];
    float4* L1Wl = (float4*)dyn;                // 80 f4
    float4* L1Bl = L1Wl + NU;                   // 80 f4
    float* cst  = (float*)(L1Bl + NU);          // 80
    float* b2l  = cst + NU;                     // 80
    float* b3l  = b2l + NU;                     // 80
    float* W4l  = b3l + NU;                     // 80
    float* hbuf = W4l + NU;                     // 80*128 = 10240 floats
    float (*S2T)[NN + 4] = (float(*)[NN + 4])hbuf;   // aliases hbuf (disjoint lifetime)

    __shared__ float CpN[2][NN][NN + 4];
    __shared__ float4 featS[128];               // {DE, ratio, Sv, ex} per cell
    __shared__ float2 a4b2[8][64];
    __shared__ float EL[2][NN];
    __shared__ int   kkL[2][NN];
    __shared__ double phre[NN], phim[NN], redl[NN], nreS[NN], nimS[NN];
    __shared__ float phi2l[NN];

    const int tid  = threadIdx.x;
    const int b    = blockIdx.x >> 3;           // sibling sets consecutive
    const int iblk = blockIdx.x & 7;
    const int j0   = iblk * 4;                  // owns columns j0..j0+3
    const int ug   = __builtin_amdgcn_readfirstlane(tid >> 6);  // uniform wave id
    const int rg   = tid & 63;                  // handles rows 2*rg, 2*rg+1
    const int U    = ug * 10;

    const float kbt = KBOLTZ * Tarr[b];
    const float er  = ErA[b];
    const float cti = ctA[b];
    const double dtb = (double)dtA[b];
    const float b4s = b4v[0];

    const float4* W2g = (const float4*)(W2p + (size_t)ug * (NKB * 48));
    const float4* W3g = (const float4*)(W3p + (size_t)ug * (NKB * 48));

    // ---- stage small loop-invariant tables into LDS (once) ----
    if (tid < NU) {
        L1Wl[tid] = L1W4g[tid];
        L1Bl[tid] = L1B4g[tid];
        b2l[tid] = bpad[tid];
        b3l[tid] = bpad[NU + tid];
        W4l[tid] = bpad[2 * NU + tid];
    }
    __syncthreads();
    if (tid < NU) {     // per-b constant part of layer-1 preactivation
        float4 lb = L1Bl[tid];
        cst[tid] = lb.w + lb.x * kbt + lb.y * er + lb.z * cti;
    }

    // ---- prime: C_0, C_1, E[0], E[1], kk[0]; init phiB; featS for s=1 ----
    {
        const float* c0g = CT_all + (size_t)b * NT1 * NN * NN;
        const float* c1g = c0g + NN * NN;
        for (int e = tid; e < NN * NN; e += 512) {
            CpN[0][e >> 5][e & 31] = c0g[e];
            CpN[1][e >> 5][e & 31] = c1g[e];
        }
        if (tid < NN) {
            EL[0][tid] = E_all[((size_t)b * NT1 + 0) * NN + tid];
            EL[1][tid] = E_all[((size_t)b * NT1 + 1) * NN + tid];
            kkL[1][tid] = kk_all[(size_t)b * NSTEPS * NN + tid];
        }
        __syncthreads();
        if (tid < NN) {
            const int i = tid;
            double acc = 0.0;
            for (int j = 0; j < NN; ++j) acc += (double)CpN[0][i][j] * (double)psi0[b * NN + j];
            phre[i] = acc; phim[i] = 0.0;
            phi2l[i] = (float)(acc * acc);
            if (iblk == 0) {
                float p0 = psi0[b * NN + i];
                out[((size_t)b * 61) * NN + i] = p0 * p0;
            }
        }
        __syncthreads();
        {   // features for step 1: Sv/DE/ex, 4 lanes per cell (128 cells)
            const int r = tid >> 2, c = tid & 3;
            const int i = r & 31, j = j0 + (r >> 5);
            float Sv = 0.f;
            #pragma unroll
            for (int m = c; m < NN; m += 4)
                Sv += CpN[1][i][m] * CpN[0][j][m];
            Sv += __shfl_xor(Sv, 1); Sv += __shfl_xor(Sv, 2);
            if (c == 0) {
                const int kj = kkL[1][j];
                const float DE = (i == kj) ? 0.f : (EL[1][i] - EL[0][j]);
                featS[r] = make_float4(DE, 100.f, Sv, __expf(DE / kbt));
            }
        }
        __syncthreads();
        if (tid < 128) {    // ratio for step 1
            const int i = tid & 31, j = j0 + (tid >> 5);
            const float p_i = phi2l[i], p_j = phi2l[j];
            featS[tid].y = (p_j > 0.01f * p_i) ? (p_i / p_j) : 100.f;
        }
    }

    for (int t = 1; t <= NSTEPS; ++t) {
        __syncthreads();                        // featS / phi2l visible
        const int cur = t & 1;

        // ---- issue prefetch loads for step t+1 (retire during MLP) ----
        float2 cpre = make_float2(0.f, 0.f);
        float  epre = 0.f;
        int    kpre = 0;
        if (t < NSTEPS) {
            const float* c1g = CT_all + ((size_t)b * NT1 + t + 1) * (NN * NN);
            cpre = ((const float2*)c1g)[tid];
            if (tid < NN) epre = E_all[((size_t)b * NT1 + t + 1) * NN + tid];
            else if (tid < 2 * NN) kpre = kk_all[((size_t)b * NSTEPS + t) * NN + (tid - NN)];
        }

        // ---- layer 1 (features -> h1), tile 10u x 2r ----
        {
            float4 f0 = featS[2 * rg], f1 = featS[2 * rg + 1];
            #pragma unroll
            for (int u = 0; u < 10; ++u) {
                float4 wv = L1Wl[U + u];
                float c = cst[U + u];
                float2 hv;
                hv.x = elu1(c + wv.x * f0.x + wv.y * f0.y + wv.z * f0.z + wv.w * f0.w);
                hv.y = elu1(c + wv.x * f1.x + wv.y * f1.y + wv.z * f1.z + wv.w * f1.w);
                *(float2*)(hbuf + (U + u) * 128 + 2 * rg) = hv;
            }
        }
        __syncthreads();

        // ---- layer 2 (h1 -> h2): weights via wave-uniform scalar loads ----
        float2 acc[10];
        #pragma unroll
        for (int u = 0; u < 10; ++u) { float bb = b2l[U + u]; acc[u] = make_float2(bb, bb); }
        for (int kb = 0; kb < NKB; ++kb) {
            float4 wv[12];
            float2 hv[4];
            #pragma unroll
            for (int m = 0; m < 12; ++m) wv[m] = W2g[kb * 12 + m];   // uniform -> s_load
            #pragma unroll
            for (int kk = 0; kk < 4; ++kk)
                hv[kk] = *(const float2*)(hbuf + (kb * 4 + kk) * 128 + 2 * rg);
            #pragma unroll
            for (int kk = 0; kk < 4; ++kk) {
                const float* wf = (const float*)&wv[kk * 3];
                #pragma unroll
                for (int u = 0; u < 10; ++u) {
                    float wS = wf[u];
                    acc[u].x += wS * hv[kk].x; acc[u].y += wS * hv[kk].y;
                }
            }
        }
        __syncthreads();    // all reads of h1 done before overwriting hbuf
        #pragma unroll
        for (int u = 0; u < 10; ++u) {
            float2 hv; hv.x = elu1(acc[u].x); hv.y = elu1(acc[u].y);
            *(float2*)(hbuf + (U + u) * 128 + 2 * rg) = hv;
        }
        __syncthreads();

        // ---- layer 3 (h2 -> h3 in registers) ----
        #pragma unroll
        for (int u = 0; u < 10; ++u) { float bb = b3l[U + u]; acc[u] = make_float2(bb, bb); }
        for (int kb = 0; kb < NKB; ++kb) {
            float4 wv[12];
            float2 hv[4];
            #pragma unroll
            for (int m = 0; m < 12; ++m) wv[m] = W3g[kb * 12 + m];   // uniform -> s_load
            #pragma unroll
            for (int kk = 0; kk < 4; ++kk)
                hv[kk] = *(const float2*)(hbuf + (kb * 4 + kk) * 128 + 2 * rg);
            #pragma unroll
            for (int kk = 0; kk < 4; ++kk) {
                const float* wf = (const float*)&wv[kk * 3];
                #pragma unroll
                for (int u = 0; u < 10; ++u) {
                    float wS = wf[u];
                    acc[u].x += wS * hv[kk].x; acc[u].y += wS * hv[kk].y;
                }
            }
        }
        // ---- layer 4 partials ----
        {
            float2 p4 = make_float2(0.f, 0.f);
            #pragma unroll
            for (int u = 0; u < 10; ++u) {
                float w4 = W4l[U + u];
                p4.x += w4 * elu1(acc[u].x); p4.y += w4 * elu1(acc[u].y);
            }
            a4b2[ug][rg] = p4;
        }
        __syncthreads();

        // ---- finalize corr, IN-REGISTER column correction, coherent store,
        //      per-wave early signal (waves 0-1 own the 128 cells) ----
        if (tid < 128) {
            const int r = tid;
            const int i = r & 31;
            const int j = j0 + (r >> 5);
            float a4 = b4s;
            #pragma unroll
            for (int g = 0; g < 8; ++g) {
                float2 pv = a4b2[g][r >> 1];
                a4 += (r & 1) ? pv.y : pv.x;
            }
            const float corr = elu1(a4) + 1.f;
            float s2v = featS[r].z * corr;
            const int kj = kkL[cur][j];
            double v = (double)s2v;
            double cd = (i == kj) ? 0.0 : v * v;        // reduce over i (32 lanes)
            cd += __shfl_xor(cd, 1);  cd += __shfl_xor(cd, 2);
            cd += __shfl_xor(cd, 4);  cd += __shfl_xor(cd, 8);
            cd += __shfl_xor(cd, 16);
            if (i == kj) {
                double nrm = fabs(v); nrm = (nrm > 0.0) ? nrm : 1.0;
                double rem = 1.0 - cd;
                s2v = (float)((rem > 0.0) ? (sqrt(rem) * v / nrm) : v);
            }
            __hip_atomic_store(&S2T_g[(((size_t)cur * NB + b) * NN + j) * NN + i],
                               s2v, __ATOMIC_RELAXED, __HIP_MEMORY_SCOPE_AGENT);
            asm volatile("s_waitcnt vmcnt(0)" ::: "memory");    // per-wave drain
            if ((tid & 63) == 0)    // each storing wave signals after ITS drain
                __hip_atomic_fetch_add(cnt + (size_t)b * NSTEPS + (t - 1), 1u,
                                       __ATOMIC_RELAXED, __HIP_MEMORY_SCOPE_AGENT);
        }

        // ---- commit prefetch into dead ping-pong slots ----
        if (t < NSTEPS) {
            const int e0 = tid * 2;
            CpN[1 - cur][e0 >> 5][e0 & 31] = cpre.x;
            CpN[1 - cur][e0 >> 5][(e0 & 31) + 1] = cpre.y;
            if (tid < NN) EL[1 - cur][tid] = epre;
            else if (tid < 2 * NN) kkL[1 - cur][tid - NN] = kpre;
        }
        __syncthreads();

        // ---- features for t+1 (Sv/DE/ex) — hidden inside the spin window ----
        if (t < NSTEPS) {
            const int curS = 1 - cur;
            const int r = tid >> 2, c = tid & 3;
            const int i = r & 31, j = j0 + (r >> 5);
            float Sv = 0.f;
            #pragma unroll
            for (int m = c; m < NN; m += 4)
                Sv += CpN[curS][i][m] * CpN[1 - curS][j][m];
            Sv += __shfl_xor(Sv, 1); Sv += __shfl_xor(Sv, 2);
            if (c == 0) {
                const int kj = kkL[curS][j];
                const float DE = (i == kj) ? 0.f : (EL[curS][i] - EL[1 - curS][j]);
                featS[r] = make_float4(DE, 100.f, Sv, __expf(DE / kbt));
            }
        }

        // ---- sibling barrier: wait for 2 signals x 8 siblings ----
        if (tid == 0) {
            const unsigned int* c = cnt + (size_t)b * NSTEPS + (t - 1);
            while (__hip_atomic_load(c, __ATOMIC_RELAXED, __HIP_MEMORY_SCOPE_AGENT)
                   < 2u * NIB) {
                __builtin_amdgcn_s_sleep(4);    // ~256cyc between polls
            }
        }
        __syncthreads();

        // ---- load corrected S2^T via 8B coherent loads (hbuf dead; aliased) ----
        {
            const unsigned long long* s2u = (const unsigned long long*)
                (S2T_g + ((size_t)cur * NB + b) * (NN * NN));
            for (int e = tid; e < (NN * NN) / 2; e += 512) {
                unsigned long long w = __hip_atomic_load(&s2u[e], __ATOMIC_RELAXED,
                                                         __HIP_MEMORY_SCOPE_AGENT);
                float2 f = *(float2*)&w;
                const int e0 = e * 2;
                S2T[e0 >> 5][e0 & 31] = f.x;
                S2T[e0 >> 5][(e0 & 31) + 1] = f.y;
            }
        }
        __syncthreads();

        // ---- phiB <- phase(E_t) * (S2' @ phiB): 32 rows x 16 lanes ----
        {
            const int ii = tid >> 4, l = tid & 15;
            double are = 0.0, aim = 0.0;
            #pragma unroll
            for (int jj = l; jj < NN; jj += 16) {
                double sv = (double)S2T[jj][ii];
                are += sv * phre[jj]; aim += sv * phim[jj];
            }
            are += __shfl_xor(are, 1); aim += __shfl_xor(aim, 1);
            are += __shfl_xor(are, 2); aim += __shfl_xor(aim, 2);
            are += __shfl_xor(are, 4); aim += __shfl_xor(aim, 4);
            are += __shfl_xor(are, 8); aim += __shfl_xor(aim, 8);
            if (l == 0) {
                double th = (double)EL[cur][ii] * (TWO_PI * ICM2IFS) * dtb;   // |th| < ~0.1
                double x2 = th * th;        // poly sincos, |err| ~1e-16 at this range
                double sph = th * (1.0 + x2 * (-1.0 / 6.0 + x2 * (1.0 / 120.0 + x2 * (-1.0 / 5040.0 + x2 * (1.0 / 362880.0)))));
                double cph = 1.0 + x2 * (-0.5 + x2 * (1.0 / 24.0 + x2 * (-1.0 / 720.0 + x2 * (1.0 / 40320.0))));
                double nre = cph * are + sph * aim;            // exp(-iEw) = c - i s
                double nim = cph * aim - sph * are;
                nreS[ii] = nre; nimS[ii] = nim;
                redl[ii] = nre * nre + nim * nim;
            }
        }
        __syncthreads();

        // ---- normalize (32-lane butterfly), update carry + phi2 ----
        if (tid < NN) {
            double v = redl[tid];
            v += __shfl_xor(v, 1); v += __shfl_xor(v, 2); v += __shfl_xor(v, 4);
            v += __shfl_xor(v, 8); v += __shfl_xor(v, 16);
            double sc = 1.0 / sqrt(v);
            double nr = nreS[tid] * sc, ni = nimS[tid] * sc;
            phre[tid] = nr; phim[tid] = ni;
            phi2l[tid] = (float)(nr * nr + ni * ni);
        }
        __syncthreads();

        // ---- ploc (every NSI steps, 4 rows per sibling) + ratio finalize ----
        if ((t % NSI) == 0 && tid < 64) {
            const int ii = iblk * 4 + (tid >> 4), l = tid & 15;
            double are = 0.0, aim = 0.0;
            #pragma unroll
            for (int jj = l; jj < NN; jj += 16) {
                double cij = (double)CpN[cur][jj][ii];   // C_t[i][j] = CT_t[j][i]
                are += cij * phre[jj]; aim += cij * phim[jj];
            }
            are += __shfl_xor(are, 1); aim += __shfl_xor(aim, 1);
            are += __shfl_xor(are, 2); aim += __shfl_xor(aim, 2);
            are += __shfl_xor(are, 4); aim += __shfl_xor(aim, 4);
            are += __shfl_xor(are, 8); aim += __shfl_xor(aim, 8);
            if (l == 0)
                out[((size_t)b * 61 + t / NSI) * NN + ii] = (float)(are * are + aim * aim);
        }
        if (t < NSTEPS && tid < 128) {     // ratio for t+1 (needs fresh phi2l)
            const int i = tid & 31, j = j0 + (tid >> 5);
            const float p_i = phi2l[i], p_j = phi2l[j];
            featS[tid].y = (p_j > 0.01f * p_i) ? (p_i / p_j) : 100.f;
        }
    }
}

// ---------------------------------------------------------------------------
extern "C" void kernel_launch(void* const* d_in, const int* in_sizes, int n_in,
                              void* d_out, int out_size, void* d_ws, size_t ws_size,
                              hipStream_t stream)
{
    const float* Tarr = (const float*)d_in[0];
    const float* ErA  = (const float*)d_in[1];
    const float* ctA  = (const float*)d_in[2];
    const float* dtA  = (const float*)d_in[4];
    const float* psi0 = (const float*)d_in[6];
    const float* Hf   = (const float*)d_in[7];
    const float* W1   = (const float*)d_in[8];
    const float* b1   = (const float*)d_in[9];
    const float* W2   = (const float*)d_in[10];
    const float* b2   = (const float*)d_in[11];
    const float* W3   = (const float*)d_in[12];
    const float* b3   = (const float*)d_in[13];
    const float* W4   = (const float*)d_in[14];
    const float* b4   = (const float*)d_in[15];

    unsigned int* cnt = (unsigned int*)d_ws;                    // 32*600 counters
    float* E_all  = (float*)(cnt + (size_t)NB * NSTEPS);        // 32*601*32
    float* CT_all = E_all + (size_t)NB * NT1 * NN;              // 32*601*32*32
    float* W2p    = CT_all + (size_t)NB * NT1 * NN * NN;        // 7680
    float* W3p    = W2p + 8 * NKB * 48;                         // 7680
    float4* L1W4  = (float4*)(W3p + 8 * NKB * 48);              // 80 f4
    float4* L1B4  = L1W4 + NU;                                  // 80 f4
    float* bpad   = (float*)(L1B4 + NU);                        // 3*80
    float* S2T_g  = bpad + 3 * NU;                              // 2*32*32*32
    int*   kk_all = (int*)(S2T_g + 2 * (size_t)NB * NN * NN);   // 32*600*32
    float* outp   = (float*)d_out;

    hipMemsetAsync(cnt, 0, (size_t)NB * NSTEPS * sizeof(unsigned int), stream);
    eigh_kernel<<<NB * NT1, 64, 0, stream>>>(Hf, E_all, CT_all);
    wtrans_kernel<<<1, 256, 0, stream>>>(W1, b1, W2, W3, b2, b3, W4,
                                         W2p, W3p, L1W4, L1B4, bpad);
    kk_kernel<<<NB * NSTEPS, 256, 0, stream>>>(CT_all, kk_all);

    // dyn LDS: two f4 tables (80 each) + 4x80 biases + hbuf 80*128
    const size_t dynf = (size_t)(8 * NU) + 4 * NU + NU * 128;
    persist_kernel<<<NB * NIB, 512, dynf * sizeof(float), stream>>>(E_all, CT_all,
        kk_all, psi0, Tarr, ErA, ctA, dtA, W2p, W3p, L1W4, L1B4, bpad, b4,
        S2T_g, cnt, outp);
}

// Round 7
// 13703.830 us; speedup vs baseline: 9.5639x; 1.0688x over previous
//
#include <hip/hip_runtime.h>
#include <math.h>

// R7 = R6 resubmission (R6 bench was an infra failure: "container failed
// twice", no pytest verdict / profile produced; source audit found no
// deadlock or alignment hazard).

#define NB 32
#define NN 32
#define NSTEPS 600
#define NT1 601
#define NSI 10
#define NH 75
#define NU 80      // padded u (8 groups x 10)
#define NKB 20     // padded k-blocks of 4 (k padded 75 -> 80)
#define NIB 8      // sibling blocks per batch element (grid = 256 = #CUs)

#define ICM2IFS 2.99792458e-05
#define KBOLTZ 0.6950389f
#define TWO_PI 6.283185307179586476925286766559

__device__ __forceinline__ float elu1(float x) { return x > 0.f ? x : (__expf(x) - 1.f); }

// ---------------------------------------------------------------------------
// Phase A: batched 32x32 symmetric eigensolver (parallel cyclic Jacobi).
// R16: 128 threads (2 waves) per matrix — halves row/col phase trips per wave
// and doubles resident waves/CU (LDS-capped ~11 blocks -> 22 waves/CU).
// Arithmetic is BIT-IDENTICAL to the 64-thread version: identical task sets
// (independent within a phase), and every norm reduction keeps the original
// 64-lane mapping/order (guarded tid<64).
// ---------------------------------------------------------------------------
__global__ __launch_bounds__(128) void eigh_kernel(const float* __restrict__ Hf,
                                                   float* __restrict__ E_all,
                                                   float* __restrict__ CT_all)
{
    __shared__ double A[NN][NN + 1];
    __shared__ float  V[NN][NN + 1];
    __shared__ double csC[16], csS[16];
    __shared__ int   prC[16], qrC[16];
    __shared__ double redv;
    __shared__ int   rankl[NN];

    const int idx = blockIdx.x;      // b*601 + t
    const int tid = threadIdx.x;
    const float* Hp = Hf + (size_t)idx * (NN * NN);

    for (int e = tid; e < NN * NN; e += 128) {
        A[e >> 5][e & 31] = (double)Hp[e];
        V[e >> 5][e & 31] = ((e >> 5) == (e & 31)) ? 1.f : 0.f;
    }
    __syncthreads();

    if (tid < 64) {                 // original 64-lane mapping -> identical tol2
        double part = 0.0;
        for (int e = tid; e < NN * NN; e += 64) { double v = A[e >> 5][e & 31]; part += v * v; }
        #pragma unroll
        for (int off = 32; off > 0; off >>= 1) part += __shfl_down(part, off);
        if (tid == 0) redv = part;
    }
    __syncthreads();
    const double tol2 = 1e-20 * redv;

    for (int sweep = 0; sweep < 10; ++sweep) {
        for (int r = 0; r < NN - 1; ++r) {
            if (tid < 16) {
                int m = tid, p, q;
                if (m == 0) { p = 0; q = 1 + (r % 31); }
                else { p = 1 + ((m + r) % 31); q = 1 + ((31 - m + r) % 31); }
                double apq = A[p][q];
                double c = 1.0, sn = 0.0;
                if (apq != 0.0) {
                    double theta = 0.5 * (A[q][q] - A[p][p]) / apq;
                    double tt = 1.0 / (fabs(theta) + sqrt(theta * theta + 1.0));
                    if (theta < 0.0) tt = -tt;
                    c = 1.0 / sqrt(tt * tt + 1.0);
                    sn = tt * c;
                }
                csC[m] = c; csS[m] = sn; prC[m] = p; qrC[m] = q;
            }
            __syncthreads();
            #pragma unroll
            for (int it = 0; it < 4; ++it) {          // rows: A <- J^T A (512 tasks)
                int task = tid + it * 128;
                int m = task >> 5, jc = task & 31;
                int p = prC[m], q = qrC[m];
                double c = csC[m], sn = csS[m];
                double ap = A[p][jc], aq = A[q][jc];
                A[p][jc] = c * ap - sn * aq;
                A[q][jc] = sn * ap + c * aq;
            }
            __syncthreads();
            #pragma unroll
            for (int it = 0; it < 8; ++it) {          // cols: A (f64) + V (f32), 1024 tasks
                int task = tid + it * 128;
                int m = (task >> 5) & 15, ir = task & 31;
                int p = prC[m], q = qrC[m];
                if (task < 512) {
                    double c = csC[m], sn = csS[m];
                    double aip = A[ir][p], aiq = A[ir][q];
                    A[ir][p] = c * aip - sn * aiq;
                    A[ir][q] = sn * aip + c * aiq;
                } else {
                    float cf = (float)csC[m], sf = (float)csS[m];
                    float vip = V[ir][p], viq = V[ir][q];
                    V[ir][p] = cf * vip - sf * viq;
                    V[ir][q] = sf * vip + cf * viq;
                }
            }
            __syncthreads();
        }
        if (sweep >= 3) {
            if (tid < 64) {         // original 64-lane mapping -> identical redv
                double o = 0.0;
                for (int e = tid; e < NN * NN; e += 64) {
                    int i2 = e >> 5, j2 = e & 31;
                    double v = A[i2][j2];
                    o += (i2 != j2) ? v * v : 0.0;
                }
                #pragma unroll
                for (int off = 32; off > 0; off >>= 1) o += __shfl_down(o, off);
                if (tid == 0) redv = o;
            }
            __syncthreads();
            if (redv <= tol2) break;
        }
    }
    __syncthreads();

    if (tid < NN) {
        double ei = A[tid][tid];
        int rk = 0;
        for (int j2 = 0; j2 < NN; ++j2) {
            double ej = A[j2][j2];
            rk += (ej < ei || (ej == ei && j2 < tid)) ? 1 : 0;
        }
        rankl[tid] = rk;
        E_all[(size_t)idx * NN + rk] = (float)ei;
    }
    __syncthreads();
    float* ct = CT_all + (size_t)idx * NN * NN;
    for (int e = tid; e < NN * NN; e += 128) {
        int col = e >> 5, m2 = e & 31;
        ct[(size_t)rankl[col] * NN + m2] = V[m2][col];
    }
}

// ---------------------------------------------------------------------------
// Phase A2: kk[b,s,j] = argmax_i S[b,s,i,j]^2 (first index on ties)
// ---------------------------------------------------------------------------
__global__ __launch_bounds__(256) void kk_kernel(const float* __restrict__ CT_all,
                                                 int* __restrict__ kk_all)
{
    __shared__ float Ct[NN][NN + 1], Cp[NN][NN + 1], S[NN][NN + 1];
    const int blk = blockIdx.x;                // b*600 + (s-1)
    const int b = blk / NSTEPS, s = blk % NSTEPS + 1;
    const int tid = threadIdx.x;
    const float* ctg = CT_all + ((size_t)b * NT1 + s) * (NN * NN);
    const float* cpg = CT_all + ((size_t)b * NT1 + s - 1) * (NN * NN);
    for (int e = tid; e < NN * NN; e += 256) {
        Ct[e >> 5][e & 31] = ctg[e];
        Cp[e >> 5][e & 31] = cpg[e];
    }
    __syncthreads();
    for (int e = tid; e < NN * NN; e += 256) {
        int i = e >> 5, j = e & 31;
        float acc = 0.f;
        for (int m = 0; m < NN; ++m) acc += Ct[i][m] * Cp[j][m];
        S[i][j] = acc;
    }
    __syncthreads();
    if (tid < NN) {
        const int j = tid;
        float best = -1.f; int bi = 0;
        for (int i = 0; i < NN; ++i) {
            float v = S[i][j]; v *= v;
            if (v > best) { best = v; bi = i; }
        }
        kk_all[(size_t)blk * NN + j] = bi;
    }
}

// ---------------------------------------------------------------------------
// Pack weights: Wp[ug 8][kb 20][kp 4][12] (10 u + 2 pad, 16B rows; zero pad).
// ---------------------------------------------------------------------------
__global__ void wtrans_kernel(const float* __restrict__ W1, const float* __restrict__ b1,
                              const float* __restrict__ W2, const float* __restrict__ W3,
                              const float* __restrict__ b2, const float* __restrict__ b3,
                              const float* __restrict__ W4,
                              float* __restrict__ W2p, float* __restrict__ W3p,
                              float4* __restrict__ L1W4, float4* __restrict__ L1B4,
                              float* __restrict__ bpad)
{
    const int tid = threadIdx.x;
    const int tot = 8 * NKB * 4 * 12;          // 7680
    for (int e = tid; e < tot; e += 256) {
        int ug = e / (NKB * 4 * 12);
        int kb = (e / (4 * 12)) % NKB;
        int kp = (e / 12) & 3;
        int uu = e % 12;
        int u = ug * 10 + uu;
        int k = kb * 4 + kp;
        float v2 = 0.f, v3 = 0.f;
        if (uu < 10 && u < NH && k < NH) {
            v2 = W2[u * NH + k];
            v3 = W3[u * NH + k];
        }
        W2p[e] = v2; W3p[e] = v3;
    }
    if (tid < NU) {
        if (tid < NH) {
            const float* w = W1 + tid * 8;
            L1W4[tid] = make_float4(w[0], w[1], w[2], w[7]);
            L1B4[tid] = make_float4(w[3], w[4], w[5], b1[tid]);
            bpad[tid]          = b2[tid];
            bpad[NU + tid]     = b3[tid];
            bpad[2 * NU + tid] = W4[tid];
        } else {
            L1W4[tid] = make_float4(0.f, 0.f, 0.f, 0.f);
            L1B4[tid] = make_float4(0.f, 0.f, 0.f, 0.f);
            bpad[tid] = 0.f; bpad[NU + tid] = 0.f; bpad[2 * NU + tid] = 0.f;
        }
    }
}

// ---------------------------------------------------------------------------
// Phase B persistent kernel. R16 = R15 with PARTIAL-SUM EXCHANGE:
//   The matvec sum_j S2'[i][j]*phi[j] decomposes over column owners. Each
//   sibling reduces its 4 columns PRE-barrier (pp LDS + ascending 4-term sum)
//   and exchanges 32 complex f64 partials (512B/sibling, same bytes as S2
//   rows before). Post-barrier tail collapses to: 512-lane coherent load,
//   3-level shfl sib-sum, one LDS stage, fused phase+normalize in wave 0.
//   Deletes: S2T coherent readback, S2T LDS staging + sync, 32x32 f64 matvec,
//   separate normalize phase. f64 reassociation only (f32 path untouched).
//   Spin cadence s_sleep(2).
// ---------------------------------------------------------------------------
__global__ __launch_bounds__(512, 2) void persist_kernel(
    const float* __restrict__ E_all, const float* __restrict__ CT_all,
    const int* __restrict__ kk_all, const float* __restrict__ psi0,
    const float* __restrict__ Tarr, const float* __restrict__ ErA,
    const float* __restrict__ ctA, const float* __restrict__ dtA,
    const float* __restrict__ W2p, const float* __restrict__ W3p,
    const float4* __restrict__ L1W4g, const float4* __restrict__ L1B4g,
    const float* __restrict__ bpad, const float* __restrict__ b4v,
    double* __restrict__ part_g, unsigned int* __restrict__ cnt,
    float* __restrict__ out)
{
    extern __shared__ __align__(16) float dyn[];
    float4* L1Wl = (float4*)dyn;                // 80 f4
    float4* L1Bl = L1Wl + NU;                   // 80 f4
    float* cst  = (float*)(L1Bl + NU);          // 80
    float* b2l  = cst + NU;                     // 80
    float* b3l  = b2l + NU;                     // 80
    float* W4l  = b3l + NU;                     // 80
    float* hbuf = W4l + NU;                     // 80*128 = 10240 floats

    __shared__ float CpN[2][NN][NN + 4];
    __shared__ float4 featS[128];               // {DE, ratio, Sv, ex} per cell
    __shared__ float2 a4b2[8][64];
    __shared__ float EL[2][NN];
    __shared__ int   kkL[2][NN];
    __shared__ double phre[NN], phim[NN];
    __shared__ double ppre[4][NN], ppim[4][NN]; // per-column products
    __shared__ double sre[NN], sim[NN];         // sib-summed partials
    __shared__ float phi2l[NN];

    const int tid  = threadIdx.x;
    const int b    = blockIdx.x >> 3;           // sibling sets consecutive
    const int iblk = blockIdx.x & 7;
    const int j0   = iblk * 4;                  // owns columns j0..j0+3
    const int ug   = __builtin_amdgcn_readfirstlane(tid >> 6);  // uniform wave id
    const int rg   = tid & 63;                  // handles rows 2*rg, 2*rg+1
    const int U    = ug * 10;

    const float kbt = KBOLTZ * Tarr[b];
    const float er  = ErA[b];
    const float cti = ctA[b];
    const double dtb = (double)dtA[b];
    const float b4s = b4v[0];

    const float4* W2g = (const float4*)(W2p + (size_t)ug * (NKB * 48));
    const float4* W3g = (const float4*)(W3p + (size_t)ug * (NKB * 48));

    // ---- stage small loop-invariant tables into LDS (once) ----
    if (tid < NU) {
        L1Wl[tid] = L1W4g[tid];
        L1Bl[tid] = L1B4g[tid];
        b2l[tid] = bpad[tid];
        b3l[tid] = bpad[NU + tid];
        W4l[tid] = bpad[2 * NU + tid];
    }
    __syncthreads();
    if (tid < NU) {     // per-b constant part of layer-1 preactivation
        float4 lb = L1Bl[tid];
        cst[tid] = lb.w + lb.x * kbt + lb.y * er + lb.z * cti;
    }

    // ---- prime: C_0, C_1, E[0], E[1], kk[0]; init phiB; featS for s=1 ----
    {
        const float* c0g = CT_all + (size_t)b * NT1 * NN * NN;
        const float* c1g = c0g + NN * NN;
        for (int e = tid; e < NN * NN; e += 512) {
            CpN[0][e >> 5][e & 31] = c0g[e];
            CpN[1][e >> 5][e & 31] = c1g[e];
        }
        if (tid < NN) {
            EL[0][tid] = E_all[((size_t)b * NT1 + 0) * NN + tid];
            EL[1][tid] = E_all[((size_t)b * NT1 + 1) * NN + tid];
            kkL[1][tid] = kk_all[(size_t)b * NSTEPS * NN + tid];
        }
        __syncthreads();
        if (tid < NN) {
            const int i = tid;
            double acc = 0.0;
            for (int j = 0; j < NN; ++j) acc += (double)CpN[0][i][j] * (double)psi0[b * NN + j];
            phre[i] = acc; phim[i] = 0.0;
            phi2l[i] = (float)(acc * acc);
            if (iblk == 0) {
                float p0 = psi0[b * NN + i];
                out[((size_t)b * 61) * NN + i] = p0 * p0;
            }
        }
        __syncthreads();
        {   // features for step 1: Sv/DE/ex, 4 lanes per cell (128 cells)
            const int r = tid >> 2, c = tid & 3;
            const int i = r & 31, j = j0 + (r >> 5);
            float Sv = 0.f;
            #pragma unroll
            for (int m = c; m < NN; m += 4)
                Sv += CpN[1][i][m] * CpN[0][j][m];
            Sv += __shfl_xor(Sv, 1); Sv += __shfl_xor(Sv, 2);
            if (c == 0) {
                const int kj = kkL[1][j];
                const float DE = (i == kj) ? 0.f : (EL[1][i] - EL[0][j]);
                featS[r] = make_float4(DE, 100.f, Sv, __expf(DE / kbt));
            }
        }
        __syncthreads();
        if (tid < 128) {    // ratio for step 1
            const int i = tid & 31, j = j0 + (tid >> 5);
            const float p_i = phi2l[i], p_j = phi2l[j];
            featS[tid].y = (p_j > 0.01f * p_i) ? (p_i / p_j) : 100.f;
        }
    }

    for (int t = 1; t <= NSTEPS; ++t) {
        __syncthreads();                        // featS / phi2l visible
        const int cur = t & 1;

        // ---- issue prefetch loads for step t+1 (retire during MLP) ----
        float2 cpre = make_float2(0.f, 0.f);
        float  epre = 0.f;
        int    kpre = 0;
        if (t < NSTEPS) {
            const float* c1g = CT_all + ((size_t)b * NT1 + t + 1) * (NN * NN);
            cpre = ((const float2*)c1g)[tid];
            if (tid < NN) epre = E_all[((size_t)b * NT1 + t + 1) * NN + tid];
            else if (tid < 2 * NN) kpre = kk_all[((size_t)b * NSTEPS + t) * NN + (tid - NN)];
        }

        // ---- layer 1 (features -> h1), tile 10u x 2r ----
        {
            float4 f0 = featS[2 * rg], f1 = featS[2 * rg + 1];
            #pragma unroll
            for (int u = 0; u < 10; ++u) {
                float4 wv = L1Wl[U + u];
                float c = cst[U + u];
                float2 hv;
                hv.x = elu1(c + wv.x * f0.x + wv.y * f0.y + wv.z * f0.z + wv.w * f0.w);
                hv.y = elu1(c + wv.x * f1.x + wv.y * f1.y + wv.z * f1.z + wv.w * f1.w);
                *(float2*)(hbuf + (U + u) * 128 + 2 * rg) = hv;
            }
        }
        __syncthreads();

        // ---- layer 2 (h1 -> h2): weights via wave-uniform scalar loads ----
        float2 acc[10];
        #pragma unroll
        for (int u = 0; u < 10; ++u) { float bb = b2l[U + u]; acc[u] = make_float2(bb, bb); }
        for (int kb = 0; kb < NKB; ++kb) {
            float4 wv[12];
            float2 hv[4];
            #pragma unroll
            for (int m = 0; m < 12; ++m) wv[m] = W2g[kb * 12 + m];   // uniform -> s_load
            #pragma unroll
            for (int kk = 0; kk < 4; ++kk)
                hv[kk] = *(const float2*)(hbuf + (kb * 4 + kk) * 128 + 2 * rg);
            #pragma unroll
            for (int kk = 0; kk < 4; ++kk) {
                const float* wf = (const float*)&wv[kk * 3];
                #pragma unroll
                for (int u = 0; u < 10; ++u) {
                    float wS = wf[u];
                    acc[u].x += wS * hv[kk].x; acc[u].y += wS * hv[kk].y;
                }
            }
        }
        __syncthreads();    // all reads of h1 done before overwriting hbuf
        #pragma unroll
        for (int u = 0; u < 10; ++u) {
            float2 hv; hv.x = elu1(acc[u].x); hv.y = elu1(acc[u].y);
            *(float2*)(hbuf + (U + u) * 128 + 2 * rg) = hv;
        }
        __syncthreads();

        // ---- layer 3 (h2 -> h3 in registers) ----
        #pragma unroll
        for (int u = 0; u < 10; ++u) { float bb = b3l[U + u]; acc[u] = make_float2(bb, bb); }
        for (int kb = 0; kb < NKB; ++kb) {
            float4 wv[12];
            float2 hv[4];
            #pragma unroll
            for (int m = 0; m < 12; ++m) wv[m] = W3g[kb * 12 + m];   // uniform -> s_load
            #pragma unroll
            for (int kk = 0; kk < 4; ++kk)
                hv[kk] = *(const float2*)(hbuf + (kb * 4 + kk) * 128 + 2 * rg);
            #pragma unroll
            for (int kk = 0; kk < 4; ++kk) {
                const float* wf = (const float*)&wv[kk * 3];
                #pragma unroll
                for (int u = 0; u < 10; ++u) {
                    float wS = wf[u];
                    acc[u].x += wS * hv[kk].x; acc[u].y += wS * hv[kk].y;
                }
            }
        }
        // ---- layer 4 partials ----
        {
            float2 p4 = make_float2(0.f, 0.f);
            #pragma unroll
            for (int u = 0; u < 10; ++u) {
                float w4 = W4l[U + u];
                p4.x += w4 * elu1(acc[u].x); p4.y += w4 * elu1(acc[u].y);
            }
            a4b2[ug][rg] = p4;
        }
        __syncthreads();

        // ---- finalize corr, IN-REGISTER column correction, per-column
        //      complex products into LDS (pre-barrier partial reduction) ----
        if (tid < 128) {
            const int r = tid;
            const int i = r & 31;
            const int jj = r >> 5;              // 0..3
            const int j = j0 + jj;
            float a4 = b4s;
            #pragma unroll
            for (int g = 0; g < 8; ++g) {
                float2 pv = a4b2[g][r >> 1];
                a4 += (r & 1) ? pv.y : pv.x;
            }
            const float corr = elu1(a4) + 1.f;
            float s2v = featS[r].z * corr;
            const int kj = kkL[cur][j];
            double v = (double)s2v;
            double cd = (i == kj) ? 0.0 : v * v;        // reduce over i (32 lanes)
            cd += __shfl_xor(cd, 1);  cd += __shfl_xor(cd, 2);
            cd += __shfl_xor(cd, 4);  cd += __shfl_xor(cd, 8);
            cd += __shfl_xor(cd, 16);
            if (i == kj) {
                double nrm = fabs(v); nrm = (nrm > 0.0) ? nrm : 1.0;
                double rem = 1.0 - cd;
                v = (rem > 0.0) ? (sqrt(rem) * v / nrm) : v;
                v = (double)(float)v;           // keep f32 rounding as before
            }
            ppre[jj][i] = v * phre[j];
            ppim[jj][i] = v * phim[j];
        }

        // ---- commit prefetch into dead ping-pong slots ----
        if (t < NSTEPS) {
            const int e0 = tid * 2;
            CpN[1 - cur][e0 >> 5][e0 & 31] = cpre.x;
            CpN[1 - cur][e0 >> 5][(e0 & 31) + 1] = cpre.y;
            if (tid < NN) EL[1 - cur][tid] = epre;
            else if (tid < 2 * NN) kkL[1 - cur][tid - NN] = kpre;
        }
        __syncthreads();

        // ---- sum own 4 columns, coherent-store partials, signal (wave 0) ----
        if (tid < 32) {
            const int i = tid;
            double pr = ((ppre[0][i] + ppre[1][i]) + ppre[2][i]) + ppre[3][i];
            double pi = ((ppim[0][i] + ppim[1][i]) + ppim[2][i]) + ppim[3][i];
            double* pg = part_g + ((size_t)cur * NB + b) * 512;
            __hip_atomic_store(&pg[i * 8 + iblk], pr,
                               __ATOMIC_RELAXED, __HIP_MEMORY_SCOPE_AGENT);
            __hip_atomic_store(&pg[256 + i * 8 + iblk], pi,
                               __ATOMIC_RELAXED, __HIP_MEMORY_SCOPE_AGENT);
            asm volatile("s_waitcnt vmcnt(0)" ::: "memory");    // drain (wave 0)
            if (tid == 0)
                __hip_atomic_fetch_add(cnt + (size_t)b * NSTEPS + (t - 1), 1u,
                                       __ATOMIC_RELAXED, __HIP_MEMORY_SCOPE_AGENT);
        }

        // ---- features for t+1 (Sv/DE/ex) — hidden inside the spin window ----
        if (t < NSTEPS) {
            const int curS = 1 - cur;
            const int r = tid >> 2, c = tid & 3;
            const int i = r & 31, j = j0 + (r >> 5);
            float Sv = 0.f;
            #pragma unroll
            for (int m = c; m < NN; m += 4)
                Sv += CpN[curS][i][m] * CpN[1 - curS][j][m];
            Sv += __shfl_xor(Sv, 1); Sv += __shfl_xor(Sv, 2);
            if (c == 0) {
                const int kj = kkL[curS][j];
                const float DE = (i == kj) ? 0.f : (EL[curS][i] - EL[1 - curS][j]);
                featS[r] = make_float4(DE, 100.f, Sv, __expf(DE / kbt));
            }
        }

        // ---- sibling barrier: wait for 8 arrivals ----
        if (tid == 0) {
            const unsigned int* c = cnt + (size_t)b * NSTEPS + (t - 1);
            while (__hip_atomic_load(c, __ATOMIC_RELAXED, __HIP_MEMORY_SCOPE_AGENT)
                   < (unsigned)NIB) {
                __builtin_amdgcn_s_sleep(2);    // ~128cyc between polls
            }
        }
        __syncthreads();

        // ---- gather partials: tid = comp*256 + i*8 + sib; 3-level sib-sum ----
        {
            const double* pg = part_g + ((size_t)cur * NB + b) * 512;
            double v = __hip_atomic_load(&pg[tid], __ATOMIC_RELAXED,
                                         __HIP_MEMORY_SCOPE_AGENT);
            v += __shfl_xor(v, 1); v += __shfl_xor(v, 2); v += __shfl_xor(v, 4);
            if ((tid & 7) == 0) {
                const int i = (tid >> 3) & 31;
                if (tid < 256) sre[i] = v; else sim[i] = v;
            }
        }
        __syncthreads();

        // ---- fused phase + normalize (wave 0) ----
        if (tid < NN) {
            const int ii = tid;
            double are = sre[ii], aim = sim[ii];
            double th = (double)EL[cur][ii] * (TWO_PI * ICM2IFS) * dtb;   // |th| < ~0.1
            double x2 = th * th;        // poly sincos, |err| ~1e-16 at this range
            double sph = th * (1.0 + x2 * (-1.0 / 6.0 + x2 * (1.0 / 120.0 + x2 * (-1.0 / 5040.0 + x2 * (1.0 / 362880.0)))));
            double cph = 1.0 + x2 * (-0.5 + x2 * (1.0 / 24.0 + x2 * (-1.0 / 720.0 + x2 * (1.0 / 40320.0))));
            double nre = cph * are + sph * aim;            // exp(-iEw) = c - i s
            double nim = cph * aim - sph * are;
            double v = nre * nre + nim * nim;
            double s = v;
            s += __shfl_xor(s, 1); s += __shfl_xor(s, 2); s += __shfl_xor(s, 4);
            s += __shfl_xor(s, 8); s += __shfl_xor(s, 16);
            double sc = 1.0 / sqrt(s);
            double nr = nre * sc, ni = nim * sc;
            phre[ii] = nr; phim[ii] = ni;
            phi2l[ii] = (float)(nr * nr + ni * ni);
        }
        __syncthreads();

        // ---- ploc (every NSI steps, 4 rows per sibling) + ratio finalize ----
        if ((t % NSI) == 0 && tid < 64) {
            const int ii = iblk * 4 + (tid >> 4), l = tid & 15;
            double are = 0.0, aim = 0.0;
            #pragma unroll
            for (int jj = l; jj < NN; jj += 16) {
                double cij = (double)CpN[cur][jj][ii];   // C_t[i][j] = CT_t[j][i]
                are += cij * phre[jj]; aim += cij * phim[jj];
            }
            are += __shfl_xor(are, 1); aim += __shfl_xor(aim, 1);
            are += __shfl_xor(are, 2); aim += __shfl_xor(aim, 2);
            are += __shfl_xor(are, 4); aim += __shfl_xor(aim, 4);
            are += __shfl_xor(are, 8); aim += __shfl_xor(aim, 8);
            if (l == 0)
                out[((size_t)b * 61 + t / NSI) * NN + ii] = (float)(are * are + aim * aim);
        }
        if (t < NSTEPS && tid < 128) {     // ratio for t+1 (needs fresh phi2l)
            const int i = tid & 31, j = j0 + (tid >> 5);
            const float p_i = phi2l[i], p_j = phi2l[j];
            featS[tid].y = (p_j > 0.01f * p_i) ? (p_i / p_j) : 100.f;
        }
    }
}

// ---------------------------------------------------------------------------
extern "C" void kernel_launch(void* const* d_in, const int* in_sizes, int n_in,
                              void* d_out, int out_size, void* d_ws, size_t ws_size,
                              hipStream_t stream)
{
    const float* Tarr = (const float*)d_in[0];
    const float* ErA  = (const float*)d_in[1];
    const float* ctA  = (const float*)d_in[2];
    const float* dtA  = (const float*)d_in[4];
    const float* psi0 = (const float*)d_in[6];
    const float* Hf   = (const float*)d_in[7];
    const float* W1   = (const float*)d_in[8];
    const float* b1   = (const float*)d_in[9];
    const float* W2   = (const float*)d_in[10];
    const float* b2   = (const float*)d_in[11];
    const float* W3   = (const float*)d_in[12];
    const float* b3   = (const float*)d_in[13];
    const float* W4   = (const float*)d_in[14];
    const float* b4   = (const float*)d_in[15];

    unsigned int* cnt = (unsigned int*)d_ws;                    // 32*600 counters
    float* E_all  = (float*)(cnt + (size_t)NB * NSTEPS);        // 32*601*32
    float* CT_all = E_all + (size_t)NB * NT1 * NN;              // 32*601*32*32
    float* W2p    = CT_all + (size_t)NB * NT1 * NN * NN;        // 7680
    float* W3p    = W2p + 8 * NKB * 48;                         // 7680
    float4* L1W4  = (float4*)(W3p + 8 * NKB * 48);              // 80 f4
    float4* L1B4  = L1W4 + NU;                                  // 80 f4
    float* bpad   = (float*)(L1B4 + NU);                        // 3*80
    double* part_g = (double*)(bpad + 3 * NU);                  // 2*32*512 f64 (256KB)
    int*   kk_all = (int*)(part_g + 2 * (size_t)NB * 512);      // 32*600*32
    float* outp   = (float*)d_out;

    hipMemsetAsync(cnt, 0, (size_t)NB * NSTEPS * sizeof(unsigned int), stream);
    eigh_kernel<<<NB * NT1, 128, 0, stream>>>(Hf, E_all, CT_all);
    wtrans_kernel<<<1, 256, 0, stream>>>(W1, b1, W2, W3, b2, b3, W4,
                                         W2p, W3p, L1W4, L1B4, bpad);
    kk_kernel<<<NB * NSTEPS, 256, 0, stream>>>(CT_all, kk_all);

    // dyn LDS: two f4 tables (80 each) + 4x80 biases + hbuf 80*128
    const size_t dynf = (size_t)(8 * NU) + 4 * NU + NU * 128;
    persist_kernel<<<NB * NIB, 512, dynf * sizeof(float), stream>>>(E_all, CT_all,
        kk_all, psi0, Tarr, ErA, ctA, dtA, W2p, W3p, L1W4, L1B4, bpad, b4,
        part_g, cnt, outp);
}

// Round 8
// 13641.498 us; speedup vs baseline: 9.6076x; 1.0046x over previous
//
#include <hip/hip_runtime.h>
#include <math.h>

// R8 = R7 with kk_kernel FOLDED INTO persist (kk only ever read for a block's
// own columns; computed via 32-lane shfl argmax from the block's own Sv).

#define NB 32
#define NN 32
#define NSTEPS 600
#define NT1 601
#define NSI 10
#define NH 75
#define NU 80      // padded u (8 groups x 10)
#define NKB 20     // padded k-blocks of 4 (k padded 75 -> 80)
#define NIB 8      // sibling blocks per batch element (grid = 256 = #CUs)

#define ICM2IFS 2.99792458e-05
#define KBOLTZ 0.6950389f
#define TWO_PI 6.283185307179586476925286766559

__device__ __forceinline__ float elu1(float x) { return x > 0.f ? x : (__expf(x) - 1.f); }

// ---------------------------------------------------------------------------
// Phase A: batched 32x32 symmetric eigensolver (parallel cyclic Jacobi).
// 128 threads (2 waves) per matrix; bit-identical task sets vs 64-thr version.
// ---------------------------------------------------------------------------
__global__ __launch_bounds__(128) void eigh_kernel(const float* __restrict__ Hf,
                                                   float* __restrict__ E_all,
                                                   float* __restrict__ CT_all)
{
    __shared__ double A[NN][NN + 1];
    __shared__ float  V[NN][NN + 1];
    __shared__ double csC[16], csS[16];
    __shared__ int   prC[16], qrC[16];
    __shared__ double redv;
    __shared__ int   rankl[NN];

    const int idx = blockIdx.x;      // b*601 + t
    const int tid = threadIdx.x;
    const float* Hp = Hf + (size_t)idx * (NN * NN);

    for (int e = tid; e < NN * NN; e += 128) {
        A[e >> 5][e & 31] = (double)Hp[e];
        V[e >> 5][e & 31] = ((e >> 5) == (e & 31)) ? 1.f : 0.f;
    }
    __syncthreads();

    if (tid < 64) {                 // original 64-lane mapping -> identical tol2
        double part = 0.0;
        for (int e = tid; e < NN * NN; e += 64) { double v = A[e >> 5][e & 31]; part += v * v; }
        #pragma unroll
        for (int off = 32; off > 0; off >>= 1) part += __shfl_down(part, off);
        if (tid == 0) redv = part;
    }
    __syncthreads();
    const double tol2 = 1e-20 * redv;

    for (int sweep = 0; sweep < 10; ++sweep) {
        for (int r = 0; r < NN - 1; ++r) {
            if (tid < 16) {
                int m = tid, p, q;
                if (m == 0) { p = 0; q = 1 + (r % 31); }
                else { p = 1 + ((m + r) % 31); q = 1 + ((31 - m + r) % 31); }
                double apq = A[p][q];
                double c = 1.0, sn = 0.0;
                if (apq != 0.0) {
                    double theta = 0.5 * (A[q][q] - A[p][p]) / apq;
                    double tt = 1.0 / (fabs(theta) + sqrt(theta * theta + 1.0));
                    if (theta < 0.0) tt = -tt;
                    c = 1.0 / sqrt(tt * tt + 1.0);
                    sn = tt * c;
                }
                csC[m] = c; csS[m] = sn; prC[m] = p; qrC[m] = q;
            }
            __syncthreads();
            #pragma unroll
            for (int it = 0; it < 4; ++it) {          // rows: A <- J^T A (512 tasks)
                int task = tid + it * 128;
                int m = task >> 5, jc = task & 31;
                int p = prC[m], q = qrC[m];
                double c = csC[m], sn = csS[m];
                double ap = A[p][jc], aq = A[q][jc];
                A[p][jc] = c * ap - sn * aq;
                A[q][jc] = sn * ap + c * aq;
            }
            __syncthreads();
            #pragma unroll
            for (int it = 0; it < 8; ++it) {          // cols: A (f64) + V (f32), 1024 tasks
                int task = tid + it * 128;
                int m = (task >> 5) & 15, ir = task & 31;
                int p = prC[m], q = qrC[m];
                if (task < 512) {
                    double c = csC[m], sn = csS[m];
                    double aip = A[ir][p], aiq = A[ir][q];
                    A[ir][p] = c * aip - sn * aiq;
                    A[ir][q] = sn * aip + c * aiq;
                } else {
                    float cf = (float)csC[m], sf = (float)csS[m];
                    float vip = V[ir][p], viq = V[ir][q];
                    V[ir][p] = cf * vip - sf * viq;
                    V[ir][q] = sf * vip + cf * viq;
                }
            }
            __syncthreads();
        }
        if (sweep >= 3) {
            if (tid < 64) {         // original 64-lane mapping -> identical redv
                double o = 0.0;
                for (int e = tid; e < NN * NN; e += 64) {
                    int i2 = e >> 5, j2 = e & 31;
                    double v = A[i2][j2];
                    o += (i2 != j2) ? v * v : 0.0;
                }
                #pragma unroll
                for (int off = 32; off > 0; off >>= 1) o += __shfl_down(o, off);
                if (tid == 0) redv = o;
            }
            __syncthreads();
            if (redv <= tol2) break;
        }
    }
    __syncthreads();

    if (tid < NN) {
        double ei = A[tid][tid];
        int rk = 0;
        for (int j2 = 0; j2 < NN; ++j2) {
            double ej = A[j2][j2];
            rk += (ej < ei || (ej == ei && j2 < tid)) ? 1 : 0;
        }
        rankl[tid] = rk;
        E_all[(size_t)idx * NN + rk] = (float)ei;
    }
    __syncthreads();
    float* ct = CT_all + (size_t)idx * NN * NN;
    for (int e = tid; e < NN * NN; e += 128) {
        int col = e >> 5, m2 = e & 31;
        ct[(size_t)rankl[col] * NN + m2] = V[m2][col];
    }
}

// ---------------------------------------------------------------------------
// Pack weights: Wp[ug 8][kb 20][kp 4][12] (10 u + 2 pad, 16B rows; zero pad).
// ---------------------------------------------------------------------------
__global__ void wtrans_kernel(const float* __restrict__ W1, const float* __restrict__ b1,
                              const float* __restrict__ W2, const float* __restrict__ W3,
                              const float* __restrict__ b2, const float* __restrict__ b3,
                              const float* __restrict__ W4,
                              float* __restrict__ W2p, float* __restrict__ W3p,
                              float4* __restrict__ L1W4, float4* __restrict__ L1B4,
                              float* __restrict__ bpad)
{
    const int tid = threadIdx.x;
    const int tot = 8 * NKB * 4 * 12;          // 7680
    for (int e = tid; e < tot; e += 256) {
        int ug = e / (NKB * 4 * 12);
        int kb = (e / (4 * 12)) % NKB;
        int kp = (e / 12) & 3;
        int uu = e % 12;
        int u = ug * 10 + uu;
        int k = kb * 4 + kp;
        float v2 = 0.f, v3 = 0.f;
        if (uu < 10 && u < NH && k < NH) {
            v2 = W2[u * NH + k];
            v3 = W3[u * NH + k];
        }
        W2p[e] = v2; W3p[e] = v3;
    }
    if (tid < NU) {
        if (tid < NH) {
            const float* w = W1 + tid * 8;
            L1W4[tid] = make_float4(w[0], w[1], w[2], w[7]);
            L1B4[tid] = make_float4(w[3], w[4], w[5], b1[tid]);
            bpad[tid]          = b2[tid];
            bpad[NU + tid]     = b3[tid];
            bpad[2 * NU + tid] = W4[tid];
        } else {
            L1W4[tid] = make_float4(0.f, 0.f, 0.f, 0.f);
            L1B4[tid] = make_float4(0.f, 0.f, 0.f, 0.f);
            bpad[tid] = 0.f; bpad[NU + tid] = 0.f; bpad[2 * NU + tid] = 0.f;
        }
    }
}

// ---------------------------------------------------------------------------
// Phase B persistent kernel. R8 = R7 (partial-sum exchange) + in-kernel kk:
//   * kk[j] = argmax_i Sv[i][j]^2 computed via 32-lane shfl argmax (min-index
//     tie-break = reference's first-index) from the block's OWN Sv values.
//     kk is only ever read for own columns -> no exchange needed.
//   * DE/ex for t+1 move to the post-spin phase, co-scheduled with the fp64
//     normalize on disjoint waves (norm: tid<32; kk/DE/ex: tid 256..383).
//   * kk_kernel dispatch + kk_all prefetch deleted.
// ---------------------------------------------------------------------------
__global__ __launch_bounds__(512, 2) void persist_kernel(
    const float* __restrict__ E_all, const float* __restrict__ CT_all,
    const float* __restrict__ psi0,
    const float* __restrict__ Tarr, const float* __restrict__ ErA,
    const float* __restrict__ ctA, const float* __restrict__ dtA,
    const float* __restrict__ W2p, const float* __restrict__ W3p,
    const float4* __restrict__ L1W4g, const float4* __restrict__ L1B4g,
    const float* __restrict__ bpad, const float* __restrict__ b4v,
    double* __restrict__ part_g, unsigned int* __restrict__ cnt,
    float* __restrict__ out)
{
    extern __shared__ __align__(16) float dyn[];
    float4* L1Wl = (float4*)dyn;                // 80 f4
    float4* L1Bl = L1Wl + NU;                   // 80 f4
    float* cst  = (float*)(L1Bl + NU);          // 80
    float* b2l  = cst + NU;                     // 80
    float* b3l  = b2l + NU;                     // 80
    float* W4l  = b3l + NU;                     // 80
    float* hbuf = W4l + NU;                     // 80*128 = 10240 floats

    __shared__ float CpN[2][NN][NN + 4];
    __shared__ float4 featS[128];               // {DE, ratio, Sv, ex} per cell
    __shared__ float2 a4b2[8][64];
    __shared__ float EL[2][NN];
    __shared__ int   kkL[2][NN];
    __shared__ double phre[NN], phim[NN];
    __shared__ double ppre[4][NN], ppim[4][NN]; // per-column products
    __shared__ double sre[NN], sim[NN];         // sib-summed partials
    __shared__ float phi2l[NN];

    const int tid  = threadIdx.x;
    const int b    = blockIdx.x >> 3;           // sibling sets consecutive
    const int iblk = blockIdx.x & 7;
    const int j0   = iblk * 4;                  // owns columns j0..j0+3
    const int ug   = __builtin_amdgcn_readfirstlane(tid >> 6);  // uniform wave id
    const int rg   = tid & 63;                  // handles rows 2*rg, 2*rg+1
    const int U    = ug * 10;

    const float kbt = KBOLTZ * Tarr[b];
    const float er  = ErA[b];
    const float cti = ctA[b];
    const double dtb = (double)dtA[b];
    const float b4s = b4v[0];

    const float4* W2g = (const float4*)(W2p + (size_t)ug * (NKB * 48));
    const float4* W3g = (const float4*)(W3p + (size_t)ug * (NKB * 48));

    // ---- stage small loop-invariant tables into LDS (once) ----
    if (tid < NU) {
        L1Wl[tid] = L1W4g[tid];
        L1Bl[tid] = L1B4g[tid];
        b2l[tid] = bpad[tid];
        b3l[tid] = bpad[NU + tid];
        W4l[tid] = bpad[2 * NU + tid];
    }
    __syncthreads();
    if (tid < NU) {     // per-b constant part of layer-1 preactivation
        float4 lb = L1Bl[tid];
        cst[tid] = lb.w + lb.x * kbt + lb.y * er + lb.z * cti;
    }

    // ---- prime: C_0, C_1, E[0], E[1]; init phiB; featS+kk for s=1 ----
    {
        const float* c0g = CT_all + (size_t)b * NT1 * NN * NN;
        const float* c1g = c0g + NN * NN;
        for (int e = tid; e < NN * NN; e += 512) {
            CpN[0][e >> 5][e & 31] = c0g[e];
            CpN[1][e >> 5][e & 31] = c1g[e];
        }
        if (tid < NN) {
            EL[0][tid] = E_all[((size_t)b * NT1 + 0) * NN + tid];
            EL[1][tid] = E_all[((size_t)b * NT1 + 1) * NN + tid];
        }
        __syncthreads();
        if (tid < NN) {
            const int i = tid;
            double acc = 0.0;
            for (int j = 0; j < NN; ++j) acc += (double)CpN[0][i][j] * (double)psi0[b * NN + j];
            phre[i] = acc; phim[i] = 0.0;
            phi2l[i] = (float)(acc * acc);
            if (iblk == 0) {
                float p0 = psi0[b * NN + i];
                out[((size_t)b * 61) * NN + i] = p0 * p0;
            }
        }
        __syncthreads();
        {   // Sv for step 1: 4 lanes per cell (128 cells)
            const int r = tid >> 2, c = tid & 3;
            const int i = r & 31, j = j0 + (r >> 5);
            float Sv = 0.f;
            #pragma unroll
            for (int m = c; m < NN; m += 4)
                Sv += CpN[1][i][m] * CpN[0][j][m];
            Sv += __shfl_xor(Sv, 1); Sv += __shfl_xor(Sv, 2);
            if (c == 0) featS[r] = make_float4(0.f, 0.f, Sv, 0.f);
        }
        __syncthreads();
        if (tid < 128) {    // kk (shfl argmax) + DE + ratio + ex for step 1
            const int r = tid, i = r & 31, jj = r >> 5;
            const int j = j0 + jj;
            const float Sv = featS[r].z;
            float v2 = Sv * Sv;
            int bi = i;
            #pragma unroll
            for (int off = 16; off > 0; off >>= 1) {
                float ov = __shfl_xor(v2, off);
                int   oi = __shfl_xor(bi, off);
                if (ov > v2 || (ov == v2 && oi < bi)) { v2 = ov; bi = oi; }
            }
            if (i == 0) kkL[1][j] = bi;
            const float DE = (i == bi) ? 0.f : (EL[1][i] - EL[0][j]);
            const float p_i = phi2l[i], p_j = phi2l[j];
            const float ratio = (p_j > 0.01f * p_i) ? (p_i / p_j) : 100.f;
            featS[r] = make_float4(DE, ratio, Sv, __expf(DE / kbt));
        }
    }

    for (int t = 1; t <= NSTEPS; ++t) {
        __syncthreads();                        // featS / phi2l visible
        const int cur = t & 1;

        // ---- issue prefetch loads for step t+1 (retire during MLP) ----
        float2 cpre = make_float2(0.f, 0.f);
        float  epre = 0.f;
        if (t < NSTEPS) {
            const float* c1g = CT_all + ((size_t)b * NT1 + t + 1) * (NN * NN);
            cpre = ((const float2*)c1g)[tid];
            if (tid < NN) epre = E_all[((size_t)b * NT1 + t + 1) * NN + tid];
        }

        // ---- layer 1 (features -> h1), tile 10u x 2r ----
        {
            float4 f0 = featS[2 * rg], f1 = featS[2 * rg + 1];
            #pragma unroll
            for (int u = 0; u < 10; ++u) {
                float4 wv = L1Wl[U + u];
                float c = cst[U + u];
                float2 hv;
                hv.x = elu1(c + wv.x * f0.x + wv.y * f0.y + wv.z * f0.z + wv.w * f0.w);
                hv.y = elu1(c + wv.x * f1.x + wv.y * f1.y + wv.z * f1.z + wv.w * f1.w);
                *(float2*)(hbuf + (U + u) * 128 + 2 * rg) = hv;
            }
        }
        __syncthreads();

        // ---- layer 2 (h1 -> h2): weights via wave-uniform scalar loads ----
        float2 acc[10];
        #pragma unroll
        for (int u = 0; u < 10; ++u) { float bb = b2l[U + u]; acc[u] = make_float2(bb, bb); }
        for (int kb = 0; kb < NKB; ++kb) {
            float4 wv[12];
            float2 hv[4];
            #pragma unroll
            for (int m = 0; m < 12; ++m) wv[m] = W2g[kb * 12 + m];   // uniform -> s_load
            #pragma unroll
            for (int kk = 0; kk < 4; ++kk)
                hv[kk] = *(const float2*)(hbuf + (kb * 4 + kk) * 128 + 2 * rg);
            #pragma unroll
            for (int kk = 0; kk < 4; ++kk) {
                const float* wf = (const float*)&wv[kk * 3];
                #pragma unroll
                for (int u = 0; u < 10; ++u) {
                    float wS = wf[u];
                    acc[u].x += wS * hv[kk].x; acc[u].y += wS * hv[kk].y;
                }
            }
        }
        __syncthreads();    // all reads of h1 done before overwriting hbuf
        #pragma unroll
        for (int u = 0; u < 10; ++u) {
            float2 hv; hv.x = elu1(acc[u].x); hv.y = elu1(acc[u].y);
            *(float2*)(hbuf + (U + u) * 128 + 2 * rg) = hv;
        }
        __syncthreads();

        // ---- layer 3 (h2 -> h3 in registers) ----
        #pragma unroll
        for (int u = 0; u < 10; ++u) { float bb = b3l[U + u]; acc[u] = make_float2(bb, bb); }
        for (int kb = 0; kb < NKB; ++kb) {
            float4 wv[12];
            float2 hv[4];
            #pragma unroll
            for (int m = 0; m < 12; ++m) wv[m] = W3g[kb * 12 + m];   // uniform -> s_load
            #pragma unroll
            for (int kk = 0; kk < 4; ++kk)
                hv[kk] = *(const float2*)(hbuf + (kb * 4 + kk) * 128 + 2 * rg);
            #pragma unroll
            for (int kk = 0; kk < 4; ++kk) {
                const float* wf = (const float*)&wv[kk * 3];
                #pragma unroll
                for (int u = 0; u < 10; ++u) {
                    float wS = wf[u];
                    acc[u].x += wS * hv[kk].x; acc[u].y += wS * hv[kk].y;
                }
            }
        }
        // ---- layer 4 partials ----
        {
            float2 p4 = make_float2(0.f, 0.f);
            #pragma unroll
            for (int u = 0; u < 10; ++u) {
                float w4 = W4l[U + u];
                p4.x += w4 * elu1(acc[u].x); p4.y += w4 * elu1(acc[u].y);
            }
            a4b2[ug][rg] = p4;
        }
        __syncthreads();

        // ---- finalize corr, IN-REGISTER column correction, per-column
        //      complex products into LDS (pre-barrier partial reduction) ----
        if (tid < 128) {
            const int r = tid;
            const int i = r & 31;
            const int jj = r >> 5;              // 0..3
            const int j = j0 + jj;
            float a4 = b4s;
            #pragma unroll
            for (int g = 0; g < 8; ++g) {
                float2 pv = a4b2[g][r >> 1];
                a4 += (r & 1) ? pv.y : pv.x;
            }
            const float corr = elu1(a4) + 1.f;
            float s2v = featS[r].z * corr;
            const int kj = kkL[cur][j];
            double v = (double)s2v;
            double cd = (i == kj) ? 0.0 : v * v;        // reduce over i (32 lanes)
            cd += __shfl_xor(cd, 1);  cd += __shfl_xor(cd, 2);
            cd += __shfl_xor(cd, 4);  cd += __shfl_xor(cd, 8);
            cd += __shfl_xor(cd, 16);
            if (i == kj) {
                double nrm = fabs(v); nrm = (nrm > 0.0) ? nrm : 1.0;
                double rem = 1.0 - cd;
                v = (rem > 0.0) ? (sqrt(rem) * v / nrm) : v;
                v = (double)(float)v;           // keep f32 rounding as before
            }
            ppre[jj][i] = v * phre[j];
            ppim[jj][i] = v * phim[j];
        }

        // ---- commit prefetch into dead ping-pong slots ----
        if (t < NSTEPS) {
            const int e0 = tid * 2;
            CpN[1 - cur][e0 >> 5][e0 & 31] = cpre.x;
            CpN[1 - cur][e0 >> 5][(e0 & 31) + 1] = cpre.y;
            if (tid < NN) EL[1 - cur][tid] = epre;
        }
        __syncthreads();

        // ---- sum own 4 columns, coherent-store partials, signal (wave 0) ----
        if (tid < 32) {
            const int i = tid;
            double pr = ((ppre[0][i] + ppre[1][i]) + ppre[2][i]) + ppre[3][i];
            double pi = ((ppim[0][i] + ppim[1][i]) + ppim[2][i]) + ppim[3][i];
            double* pg = part_g + ((size_t)cur * NB + b) * 512;
            __hip_atomic_store(&pg[i * 8 + iblk], pr,
                               __ATOMIC_RELAXED, __HIP_MEMORY_SCOPE_AGENT);
            __hip_atomic_store(&pg[256 + i * 8 + iblk], pi,
                               __ATOMIC_RELAXED, __HIP_MEMORY_SCOPE_AGENT);
            asm volatile("s_waitcnt vmcnt(0)" ::: "memory");    // drain (wave 0)
            if (tid == 0)
                __hip_atomic_fetch_add(cnt + (size_t)b * NSTEPS + (t - 1), 1u,
                                       __ATOMIC_RELAXED, __HIP_MEMORY_SCOPE_AGENT);
        }

        // ---- Sv for t+1 — hidden inside the spin window ----
        if (t < NSTEPS) {
            const int curS = 1 - cur;
            const int r = tid >> 2, c = tid & 3;
            const int i = r & 31, j = j0 + (r >> 5);
            float Sv = 0.f;
            #pragma unroll
            for (int m = c; m < NN; m += 4)
                Sv += CpN[curS][i][m] * CpN[1 - curS][j][m];
            Sv += __shfl_xor(Sv, 1); Sv += __shfl_xor(Sv, 2);
            if (c == 0) featS[r] = make_float4(0.f, 0.f, Sv, 0.f);
        }

        // ---- sibling barrier: wait for 8 arrivals ----
        if (tid == 0) {
            const unsigned int* c = cnt + (size_t)b * NSTEPS + (t - 1);
            while (__hip_atomic_load(c, __ATOMIC_RELAXED, __HIP_MEMORY_SCOPE_AGENT)
                   < (unsigned)NIB) {
                __builtin_amdgcn_s_sleep(2);    // ~128cyc between polls
            }
        }
        __syncthreads();

        // ---- gather partials: tid = comp*256 + i*8 + sib; 3-level sib-sum ----
        {
            const double* pg = part_g + ((size_t)cur * NB + b) * 512;
            double v = __hip_atomic_load(&pg[tid], __ATOMIC_RELAXED,
                                         __HIP_MEMORY_SCOPE_AGENT);
            v += __shfl_xor(v, 1); v += __shfl_xor(v, 2); v += __shfl_xor(v, 4);
            if ((tid & 7) == 0) {
                const int i = (tid >> 3) & 31;
                if (tid < 256) sre[i] = v; else sim[i] = v;
            }
        }
        __syncthreads();

        // ---- fused phase + normalize (wave 0)  ||  kk+DE+ex for t+1 (waves 4-5)
        if (tid < NN) {
            const int ii = tid;
            double are = sre[ii], aim = sim[ii];
            double th = (double)EL[cur][ii] * (TWO_PI * ICM2IFS) * dtb;   // |th| < ~0.1
            double x2 = th * th;        // poly sincos, |err| ~1e-16 at this range
            double sph = th * (1.0 + x2 * (-1.0 / 6.0 + x2 * (1.0 / 120.0 + x2 * (-1.0 / 5040.0 + x2 * (1.0 / 362880.0)))));
            double cph = 1.0 + x2 * (-0.5 + x2 * (1.0 / 24.0 + x2 * (-1.0 / 720.0 + x2 * (1.0 / 40320.0))));
            double nre = cph * are + sph * aim;            // exp(-iEw) = c - i s
            double nim = cph * aim - sph * are;
            double v = nre * nre + nim * nim;
            double s = v;
            s += __shfl_xor(s, 1); s += __shfl_xor(s, 2); s += __shfl_xor(s, 4);
            s += __shfl_xor(s, 8); s += __shfl_xor(s, 16);
            double sc = 1.0 / sqrt(s);
            double nr = nre * sc, ni = nim * sc;
            phre[ii] = nr; phim[ii] = ni;
            phi2l[ii] = (float)(nr * nr + ni * ni);
        } else if (t < NSTEPS && tid >= 256 && tid < 384) {
            const int r = tid - 256;
            const int i = r & 31, jj = r >> 5;
            const int j = j0 + jj;
            const int curS = 1 - cur;
            const float Sv = featS[r].z;
            float v2 = Sv * Sv;
            int bi = i;
            #pragma unroll
            for (int off = 16; off > 0; off >>= 1) {
                float ov = __shfl_xor(v2, off);
                int   oi = __shfl_xor(bi, off);
                if (ov > v2 || (ov == v2 && oi < bi)) { v2 = ov; bi = oi; }
            }
            if (i == 0) kkL[curS][j] = bi;
            const float DE = (i == bi) ? 0.f : (EL[curS][i] - EL[cur][j]);
            featS[r].x = DE;
            featS[r].w = __expf(DE / kbt);
        }
        __syncthreads();

        // ---- ploc (every NSI steps, 4 rows per sibling) + ratio finalize ----
        if ((t % NSI) == 0 && tid < 64) {
            const int ii = iblk * 4 + (tid >> 4), l = tid & 15;
            double are = 0.0, aim = 0.0;
            #pragma unroll
            for (int jj = l; jj < NN; jj += 16) {
                double cij = (double)CpN[cur][jj][ii];   // C_t[i][j] = CT_t[j][i]
                are += cij * phre[jj]; aim += cij * phim[jj];
            }
            are += __shfl_xor(are, 1); aim += __shfl_xor(aim, 1);
            are += __shfl_xor(are, 2); aim += __shfl_xor(aim, 2);
            are += __shfl_xor(are, 4); aim += __shfl_xor(aim, 4);
            are += __shfl_xor(are, 8); aim += __shfl_xor(aim, 8);
            if (l == 0)
                out[((size_t)b * 61 + t / NSI) * NN + ii] = (float)(are * are + aim * aim);
        }
        if (t < NSTEPS && tid < 128) {     // ratio for t+1 (needs fresh phi2l)
            const int i = tid & 31, j = j0 + (tid >> 5);
            const float p_i = phi2l[i], p_j = phi2l[j];
            featS[tid].y = (p_j > 0.01f * p_i) ? (p_i / p_j) : 100.f;
        }
    }
}

// ---------------------------------------------------------------------------
extern "C" void kernel_launch(void* const* d_in, const int* in_sizes, int n_in,
                              void* d_out, int out_size, void* d_ws, size_t ws_size,
                              hipStream_t stream)
{
    const float* Tarr = (const float*)d_in[0];
    const float* ErA  = (const float*)d_in[1];
    const float* ctA  = (const float*)d_in[2];
    const float* dtA  = (const float*)d_in[4];
    const float* psi0 = (const float*)d_in[6];
    const float* Hf   = (const float*)d_in[7];
    const float* W1   = (const float*)d_in[8];
    const float* b1   = (const float*)d_in[9];
    const float* W2   = (const float*)d_in[10];
    const float* b2   = (const float*)d_in[11];
    const float* W3   = (const float*)d_in[12];
    const float* b3   = (const float*)d_in[13];
    const float* W4   = (const float*)d_in[14];
    const float* b4   = (const float*)d_in[15];

    unsigned int* cnt = (unsigned int*)d_ws;                    // 32*600 counters
    float* E_all  = (float*)(cnt + (size_t)NB * NSTEPS);        // 32*601*32
    float* CT_all = E_all + (size_t)NB * NT1 * NN;              // 32*601*32*32
    float* W2p    = CT_all + (size_t)NB * NT1 * NN * NN;        // 7680
    float* W3p    = W2p + 8 * NKB * 48;                         // 7680
    float4* L1W4  = (float4*)(W3p + 8 * NKB * 48);              // 80 f4
    float4* L1B4  = L1W4 + NU;                                  // 80 f4
    float* bpad   = (float*)(L1B4 + NU);                        // 3*80
    double* part_g = (double*)(bpad + 3 * NU);                  // 2*32*512 f64 (256KB)
    float* outp   = (float*)d_out;

    hipMemsetAsync(cnt, 0, (size_t)NB * NSTEPS * sizeof(unsigned int), stream);
    eigh_kernel<<<NB * NT1, 128, 0, stream>>>(Hf, E_all, CT_all);
    wtrans_kernel<<<1, 256, 0, stream>>>(W1, b1, W2, W3, b2, b3, W4,
                                         W2p, W3p, L1W4, L1B4, bpad);

    // dyn LDS: two f4 tables (80 each) + 4x80 biases + hbuf 80*128
    const size_t dynf = (size_t)(8 * NU) + 4 * NU + NU * 128;
    persist_kernel<<<NB * NIB, 512, dynf * sizeof(float), stream>>>(E_all, CT_all,
        psi0, Tarr, ErA, ctA, dtA, W2p, W3p, L1W4, L1B4, bpad, b4,
        part_g, cnt, outp);
}

// Round 9
// 12371.374 us; speedup vs baseline: 10.5939x; 1.1027x over previous
//
#include <hip/hip_runtime.h>
#include <math.h>

// R9: (a) REVERT R8's in-kernel kk (restored kk_kernel; R8's tree-sum argmax
// flips doubled absmax 0.0117->0.0195 for only 0.06ms). (b) persist at 1024
// threads / 16 waves (4 waves/SIMD) to hide s_load/LDS/barrier latency.
// (c) eigh tol2 1e-20 -> 1e-16 (V is f32-accumulated; off-diag < 1e-7||A||
// is invisible in output; saves ~1 sweep).

#define NB 32
#define NN 32
#define NSTEPS 600
#define NT1 601
#define NSI 10
#define NH 75
#define NU 80      // padded u
#define NKB 20     // padded k-blocks of 4 (k padded 75 -> 80)
#define NIB 8      // sibling blocks per batch element (grid = 256 = #CUs)
#define NG 16      // u-groups (16 waves x 5u)

#define ICM2IFS 2.99792458e-05
#define KBOLTZ 0.6950389f
#define TWO_PI 6.283185307179586476925286766559

__device__ __forceinline__ float elu1(float x) { return x > 0.f ? x : (__expf(x) - 1.f); }

// ---------------------------------------------------------------------------
// Phase A: batched 32x32 symmetric eigensolver (parallel cyclic Jacobi).
// 128 threads (2 waves) per matrix; bit-identical task sets vs 64-thr version.
// R9: tol2 loosened to 1e-16*||A||^2 (off-diag <= 1e-8*||A||) — V is
// accumulated in f32 so convergence below ~1e-7*||A|| cannot affect output.
// ---------------------------------------------------------------------------
__global__ __launch_bounds__(128) void eigh_kernel(const float* __restrict__ Hf,
                                                   float* __restrict__ E_all,
                                                   float* __restrict__ CT_all)
{
    __shared__ double A[NN][NN + 1];
    __shared__ float  V[NN][NN + 1];
    __shared__ double csC[16], csS[16];
    __shared__ int   prC[16], qrC[16];
    __shared__ double redv;
    __shared__ int   rankl[NN];

    const int idx = blockIdx.x;      // b*601 + t
    const int tid = threadIdx.x;
    const float* Hp = Hf + (size_t)idx * (NN * NN);

    for (int e = tid; e < NN * NN; e += 128) {
        A[e >> 5][e & 31] = (double)Hp[e];
        V[e >> 5][e & 31] = ((e >> 5) == (e & 31)) ? 1.f : 0.f;
    }
    __syncthreads();

    if (tid < 64) {                 // original 64-lane mapping -> identical tol2
        double part = 0.0;
        for (int e = tid; e < NN * NN; e += 64) { double v = A[e >> 5][e & 31]; part += v * v; }
        #pragma unroll
        for (int off = 32; off > 0; off >>= 1) part += __shfl_down(part, off);
        if (tid == 0) redv = part;
    }
    __syncthreads();
    const double tol2 = 1e-16 * redv;

    for (int sweep = 0; sweep < 10; ++sweep) {
        for (int r = 0; r < NN - 1; ++r) {
            if (tid < 16) {
                int m = tid, p, q;
                if (m == 0) { p = 0; q = 1 + (r % 31); }
                else { p = 1 + ((m + r) % 31); q = 1 + ((31 - m + r) % 31); }
                double apq = A[p][q];
                double c = 1.0, sn = 0.0;
                if (apq != 0.0) {
                    double theta = 0.5 * (A[q][q] - A[p][p]) / apq;
                    double tt = 1.0 / (fabs(theta) + sqrt(theta * theta + 1.0));
                    if (theta < 0.0) tt = -tt;
                    c = 1.0 / sqrt(tt * tt + 1.0);
                    sn = tt * c;
                }
                csC[m] = c; csS[m] = sn; prC[m] = p; qrC[m] = q;
            }
            __syncthreads();
            #pragma unroll
            for (int it = 0; it < 4; ++it) {          // rows: A <- J^T A (512 tasks)
                int task = tid + it * 128;
                int m = task >> 5, jc = task & 31;
                int p = prC[m], q = qrC[m];
                double c = csC[m], sn = csS[m];
                double ap = A[p][jc], aq = A[q][jc];
                A[p][jc] = c * ap - sn * aq;
                A[q][jc] = sn * ap + c * aq;
            }
            __syncthreads();
            #pragma unroll
            for (int it = 0; it < 8; ++it) {          // cols: A (f64) + V (f32), 1024 tasks
                int task = tid + it * 128;
                int m = (task >> 5) & 15, ir = task & 31;
                int p = prC[m], q = qrC[m];
                if (task < 512) {
                    double c = csC[m], sn = csS[m];
                    double aip = A[ir][p], aiq = A[ir][q];
                    A[ir][p] = c * aip - sn * aiq;
                    A[ir][q] = sn * aip + c * aiq;
                } else {
                    float cf = (float)csC[m], sf = (float)csS[m];
                    float vip = V[ir][p], viq = V[ir][q];
                    V[ir][p] = cf * vip - sf * viq;
                    V[ir][q] = sf * vip + cf * viq;
                }
            }
            __syncthreads();
        }
        if (sweep >= 3) {
            if (tid < 64) {         // original 64-lane mapping -> identical redv
                double o = 0.0;
                for (int e = tid; e < NN * NN; e += 64) {
                    int i2 = e >> 5, j2 = e & 31;
                    double v = A[i2][j2];
                    o += (i2 != j2) ? v * v : 0.0;
                }
                #pragma unroll
                for (int off = 32; off > 0; off >>= 1) o += __shfl_down(o, off);
                if (tid == 0) redv = o;
            }
            __syncthreads();
            if (redv <= tol2) break;
        }
    }
    __syncthreads();

    if (tid < NN) {
        double ei = A[tid][tid];
        int rk = 0;
        for (int j2 = 0; j2 < NN; ++j2) {
            double ej = A[j2][j2];
            rk += (ej < ei || (ej == ei && j2 < tid)) ? 1 : 0;
        }
        rankl[tid] = rk;
        E_all[(size_t)idx * NN + rk] = (float)ei;
    }
    __syncthreads();
    float* ct = CT_all + (size_t)idx * NN * NN;
    for (int e = tid; e < NN * NN; e += 128) {
        int col = e >> 5, m2 = e & 31;
        ct[(size_t)rankl[col] * NN + m2] = V[m2][col];
    }
}

// ---------------------------------------------------------------------------
// Phase A2: kk[b,s,j] = argmax_i S[b,s,i,j]^2 (first index on ties)
// (restored from R7 — sequential sum keeps argmax decisions matching the
// kernel that measured absmax 0.01171875)
// ---------------------------------------------------------------------------
__global__ __launch_bounds__(256) void kk_kernel(const float* __restrict__ CT_all,
                                                 int* __restrict__ kk_all)
{
    __shared__ float Ct[NN][NN + 1], Cp[NN][NN + 1], S[NN][NN + 1];
    const int blk = blockIdx.x;                // b*600 + (s-1)
    const int b = blk / NSTEPS, s = blk % NSTEPS + 1;
    const int tid = threadIdx.x;
    const float* ctg = CT_all + ((size_t)b * NT1 + s) * (NN * NN);
    const float* cpg = CT_all + ((size_t)b * NT1 + s - 1) * (NN * NN);
    for (int e = tid; e < NN * NN; e += 256) {
        Ct[e >> 5][e & 31] = ctg[e];
        Cp[e >> 5][e & 31] = cpg[e];
    }
    __syncthreads();
    for (int e = tid; e < NN * NN; e += 256) {
        int i = e >> 5, j = e & 31;
        float acc = 0.f;
        for (int m = 0; m < NN; ++m) acc += Ct[i][m] * Cp[j][m];
        S[i][j] = acc;
    }
    __syncthreads();
    if (tid < NN) {
        const int j = tid;
        float best = -1.f; int bi = 0;
        for (int i = 0; i < NN; ++i) {
            float v = S[i][j]; v *= v;
            if (v > best) { best = v; bi = i; }
        }
        kk_all[(size_t)blk * NN + j] = bi;
    }
}

// ---------------------------------------------------------------------------
// Pack weights for 16 u-groups x 5u: Wp[ug 16][kb 20][kp 4][8 (5u + 3 pad)].
// ---------------------------------------------------------------------------
__global__ void wtrans_kernel(const float* __restrict__ W1, const float* __restrict__ b1,
                              const float* __restrict__ W2, const float* __restrict__ W3,
                              const float* __restrict__ b2, const float* __restrict__ b3,
                              const float* __restrict__ W4,
                              float* __restrict__ W2p, float* __restrict__ W3p,
                              float4* __restrict__ L1W4, float4* __restrict__ L1B4,
                              float* __restrict__ bpad)
{
    const int tid = threadIdx.x;
    const int tot = NG * NKB * 4 * 8;          // 10240
    for (int e = tid; e < tot; e += 256) {
        int ug = e / (NKB * 4 * 8);
        int kb = (e / (4 * 8)) % NKB;
        int kp = (e / 8) & 3;
        int uu = e & 7;
        int u = ug * 5 + uu;
        int k = kb * 4 + kp;
        float v2 = 0.f, v3 = 0.f;
        if (uu < 5 && u < NH && k < NH) {
            v2 = W2[u * NH + k];
            v3 = W3[u * NH + k];
        }
        W2p[e] = v2; W3p[e] = v3;
    }
    if (tid < NU) {
        if (tid < NH) {
            const float* w = W1 + tid * 8;
            L1W4[tid] = make_float4(w[0], w[1], w[2], w[7]);
            L1B4[tid] = make_float4(w[3], w[4], w[5], b1[tid]);
            bpad[tid]          = b2[tid];
            bpad[NU + tid]     = b3[tid];
            bpad[2 * NU + tid] = W4[tid];
        } else {
            L1W4[tid] = make_float4(0.f, 0.f, 0.f, 0.f);
            L1B4[tid] = make_float4(0.f, 0.f, 0.f, 0.f);
            bpad[tid] = 0.f; bpad[NU + tid] = 0.f; bpad[2 * NU + tid] = 0.f;
        }
    }
}

// ---------------------------------------------------------------------------
// Phase B persistent kernel. R9 = R7 structure at 1024 threads (16 waves =
// 4 waves/SIMD): tile 5u x 2r per thread. Doubles the latency-hiding pool
// for s_load / LDS / exchange stalls at identical total VALU work and
// identical LDS traffic. Partial-sum exchange protocol unchanged from R7.
// ---------------------------------------------------------------------------
__global__ __launch_bounds__(1024) void persist_kernel(
    const float* __restrict__ E_all, const float* __restrict__ CT_all,
    const int* __restrict__ kk_all, const float* __restrict__ psi0,
    const float* __restrict__ Tarr, const float* __restrict__ ErA,
    const float* __restrict__ ctA, const float* __restrict__ dtA,
    const float* __restrict__ W2p, const float* __restrict__ W3p,
    const float4* __restrict__ L1W4g, const float4* __restrict__ L1B4g,
    const float* __restrict__ bpad, const float* __restrict__ b4v,
    double* __restrict__ part_g, unsigned int* __restrict__ cnt,
    float* __restrict__ out)
{
    extern __shared__ __align__(16) float dyn[];
    float4* L1Wl = (float4*)dyn;                // 80 f4
    float4* L1Bl = L1Wl + NU;                   // 80 f4
    float* cst  = (float*)(L1Bl + NU);          // 80
    float* b2l  = cst + NU;                     // 80
    float* b3l  = b2l + NU;                     // 80
    float* W4l  = b3l + NU;                     // 80
    float* hbuf = W4l + NU;                     // 80*128 = 10240 floats

    __shared__ float CpN[2][NN][NN + 4];
    __shared__ float4 featS[128];               // {DE, ratio, Sv, ex} per cell
    __shared__ float2 a4b2[NG][64];
    __shared__ float EL[2][NN];
    __shared__ int   kkL[2][NN];
    __shared__ double phre[NN], phim[NN];
    __shared__ double ppre[4][NN], ppim[4][NN]; // per-column products
    __shared__ double sre[NN], sim[NN];         // sib-summed partials
    __shared__ float phi2l[NN];

    const int tid  = threadIdx.x;
    const int b    = blockIdx.x >> 3;           // sibling sets consecutive
    const int iblk = blockIdx.x & 7;
    const int j0   = iblk * 4;                  // owns columns j0..j0+3
    const int ug   = __builtin_amdgcn_readfirstlane(tid >> 6);  // uniform wave id 0..15
    const int rg   = tid & 63;                  // handles cells 2*rg, 2*rg+1
    const int U    = ug * 5;

    const float kbt = KBOLTZ * Tarr[b];
    const float er  = ErA[b];
    const float cti = ctA[b];
    const double dtb = (double)dtA[b];
    const float b4s = b4v[0];

    const float4* W2g = (const float4*)(W2p + (size_t)ug * (NKB * 32));
    const float4* W3g = (const float4*)(W3p + (size_t)ug * (NKB * 32));

    // ---- stage small loop-invariant tables into LDS (once) ----
    if (tid < NU) {
        L1Wl[tid] = L1W4g[tid];
        L1Bl[tid] = L1B4g[tid];
        b2l[tid] = bpad[tid];
        b3l[tid] = bpad[NU + tid];
        W4l[tid] = bpad[2 * NU + tid];
    }
    __syncthreads();
    if (tid < NU) {     // per-b constant part of layer-1 preactivation
        float4 lb = L1Bl[tid];
        cst[tid] = lb.w + lb.x * kbt + lb.y * er + lb.z * cti;
    }

    // ---- prime: C_0, C_1, E[0], E[1], kk[0]; init phiB; featS for s=1 ----
    {
        const float* c0g = CT_all + (size_t)b * NT1 * NN * NN;
        const float* c1g = c0g + NN * NN;
        for (int e = tid; e < NN * NN; e += 1024) {
            CpN[0][e >> 5][e & 31] = c0g[e];
            CpN[1][e >> 5][e & 31] = c1g[e];
        }
        if (tid < NN) {
            EL[0][tid] = E_all[((size_t)b * NT1 + 0) * NN + tid];
            EL[1][tid] = E_all[((size_t)b * NT1 + 1) * NN + tid];
            kkL[1][tid] = kk_all[(size_t)b * NSTEPS * NN + tid];
        }
        __syncthreads();
        if (tid < NN) {
            const int i = tid;
            double acc = 0.0;
            for (int j = 0; j < NN; ++j) acc += (double)CpN[0][i][j] * (double)psi0[b * NN + j];
            phre[i] = acc; phim[i] = 0.0;
            phi2l[i] = (float)(acc * acc);
            if (iblk == 0) {
                float p0 = psi0[b * NN + i];
                out[((size_t)b * 61) * NN + i] = p0 * p0;
            }
        }
        __syncthreads();
        {   // features for step 1: Sv/DE/ex, 8 lanes per cell (128 cells x 8)
            const int r = tid >> 3, c = tid & 7;
            const int i = r & 31, j = j0 + (r >> 5);
            float Sv = 0.f;
            #pragma unroll
            for (int m = c; m < NN; m += 8)
                Sv += CpN[1][i][m] * CpN[0][j][m];
            Sv += __shfl_xor(Sv, 1); Sv += __shfl_xor(Sv, 2); Sv += __shfl_xor(Sv, 4);
            if (c == 0) {
                const int kj = kkL[1][j];
                const float DE = (i == kj) ? 0.f : (EL[1][i] - EL[0][j]);
                featS[r] = make_float4(DE, 100.f, Sv, __expf(DE / kbt));
            }
        }
        __syncthreads();
        if (tid < 128) {    // ratio for step 1
            const int i = tid & 31, j = j0 + (tid >> 5);
            const float p_i = phi2l[i], p_j = phi2l[j];
            featS[tid].y = (p_j > 0.01f * p_i) ? (p_i / p_j) : 100.f;
        }
    }

    for (int t = 1; t <= NSTEPS; ++t) {
        __syncthreads();                        // featS / phi2l visible
        const int cur = t & 1;

        // ---- issue prefetch loads for step t+1 (retire during MLP) ----
        float2 cpre = make_float2(0.f, 0.f);
        float  epre = 0.f;
        int    kpre = 0;
        if (t < NSTEPS) {
            if (tid < 512) {
                const float* c1g = CT_all + ((size_t)b * NT1 + t + 1) * (NN * NN);
                cpre = ((const float2*)c1g)[tid];
            }
            if (tid < NN) epre = E_all[((size_t)b * NT1 + t + 1) * NN + tid];
            else if (tid < 2 * NN) kpre = kk_all[((size_t)b * NSTEPS + t) * NN + (tid - NN)];
        }

        // ---- layer 1 (features -> h1), tile 5u x 2r ----
        {
            float4 f0 = featS[2 * rg], f1 = featS[2 * rg + 1];
            #pragma unroll
            for (int u = 0; u < 5; ++u) {
                float4 wv = L1Wl[U + u];
                float c = cst[U + u];
                float2 hv;
                hv.x = elu1(c + wv.x * f0.x + wv.y * f0.y + wv.z * f0.z + wv.w * f0.w);
                hv.y = elu1(c + wv.x * f1.x + wv.y * f1.y + wv.z * f1.z + wv.w * f1.w);
                *(float2*)(hbuf + (U + u) * 128 + 2 * rg) = hv;
            }
        }
        __syncthreads();

        // ---- layer 2 (h1 -> h2): weights via wave-uniform scalar loads ----
        float2 acc[5];
        #pragma unroll
        for (int u = 0; u < 5; ++u) { float bb = b2l[U + u]; acc[u] = make_float2(bb, bb); }
        for (int kb = 0; kb < NKB; ++kb) {
            float4 wv[8];
            float2 hv[4];
            #pragma unroll
            for (int m = 0; m < 8; ++m) wv[m] = W2g[kb * 8 + m];     // uniform -> s_load
            #pragma unroll
            for (int kk = 0; kk < 4; ++kk)
                hv[kk] = *(const float2*)(hbuf + (kb * 4 + kk) * 128 + 2 * rg);
            #pragma unroll
            for (int kk = 0; kk < 4; ++kk) {
                const float* wf = (const float*)&wv[kk * 2];
                #pragma unroll
                for (int u = 0; u < 5; ++u) {
                    float wS = wf[u];
                    acc[u].x += wS * hv[kk].x; acc[u].y += wS * hv[kk].y;
                }
            }
        }
        __syncthreads();    // all reads of h1 done before overwriting hbuf
        #pragma unroll
        for (int u = 0; u < 5; ++u) {
            float2 hv; hv.x = elu1(acc[u].x); hv.y = elu1(acc[u].y);
            *(float2*)(hbuf + (U + u) * 128 + 2 * rg) = hv;
        }
        __syncthreads();

        // ---- layer 3 (h2 -> h3 in registers) ----
        #pragma unroll
        for (int u = 0; u < 5; ++u) { float bb = b3l[U + u]; acc[u] = make_float2(bb, bb); }
        for (int kb = 0; kb < NKB; ++kb) {
            float4 wv[8];
            float2 hv[4];
            #pragma unroll
            for (int m = 0; m < 8; ++m) wv[m] = W3g[kb * 8 + m];     // uniform -> s_load
            #pragma unroll
            for (int kk = 0; kk < 4; ++kk)
                hv[kk] = *(const float2*)(hbuf + (kb * 4 + kk) * 128 + 2 * rg);
            #pragma unroll
            for (int kk = 0; kk < 4; ++kk) {
                const float* wf = (const float*)&wv[kk * 2];
                #pragma unroll
                for (int u = 0; u < 5; ++u) {
                    float wS = wf[u];
                    acc[u].x += wS * hv[kk].x; acc[u].y += wS * hv[kk].y;
                }
            }
        }
        // ---- layer 4 partials ----
        {
            float2 p4 = make_float2(0.f, 0.f);
            #pragma unroll
            for (int u = 0; u < 5; ++u) {
                float w4 = W4l[U + u];
                p4.x += w4 * elu1(acc[u].x); p4.y += w4 * elu1(acc[u].y);
            }
            a4b2[ug][rg] = p4;
        }
        __syncthreads();

        // ---- finalize corr, IN-REGISTER column correction, per-column
        //      complex products into LDS (pre-barrier partial reduction) ----
        if (tid < 128) {
            const int r = tid;
            const int i = r & 31;
            const int jj = r >> 5;              // 0..3
            const int j = j0 + jj;
            float a4 = b4s;
            #pragma unroll
            for (int g = 0; g < NG; ++g) {
                float2 pv = a4b2[g][r >> 1];
                a4 += (r & 1) ? pv.y : pv.x;
            }
            const float corr = elu1(a4) + 1.f;
            float s2v = featS[r].z * corr;
            const int kj = kkL[cur][j];
            double v = (double)s2v;
            double cd = (i == kj) ? 0.0 : v * v;        // reduce over i (32 lanes)
            cd += __shfl_xor(cd, 1);  cd += __shfl_xor(cd, 2);
            cd += __shfl_xor(cd, 4);  cd += __shfl_xor(cd, 8);
            cd += __shfl_xor(cd, 16);
            if (i == kj) {
                double nrm = fabs(v); nrm = (nrm > 0.0) ? nrm : 1.0;
                double rem = 1.0 - cd;
                v = (rem > 0.0) ? (sqrt(rem) * v / nrm) : v;
                v = (double)(float)v;           // keep f32 rounding as before
            }
            ppre[jj][i] = v * phre[j];
            ppim[jj][i] = v * phim[j];
        }

        // ---- commit prefetch into dead ping-pong slots ----
        if (t < NSTEPS) {
            if (tid < 512) {
                const int e0 = tid * 2;
                CpN[1 - cur][e0 >> 5][e0 & 31] = cpre.x;
                CpN[1 - cur][e0 >> 5][(e0 & 31) + 1] = cpre.y;
            }
            if (tid < NN) EL[1 - cur][tid] = epre;
            else if (tid < 2 * NN) kkL[1 - cur][tid - NN] = kpre;
        }
        __syncthreads();

        // ---- sum own 4 columns, coherent-store partials, signal (wave 0) ----
        if (tid < 32) {
            const int i = tid;
            double pr = ((ppre[0][i] + ppre[1][i]) + ppre[2][i]) + ppre[3][i];
            double pi = ((ppim[0][i] + ppim[1][i]) + ppim[2][i]) + ppim[3][i];
            double* pg = part_g + ((size_t)cur * NB + b) * 512;
            __hip_atomic_store(&pg[i * 8 + iblk], pr,
                               __ATOMIC_RELAXED, __HIP_MEMORY_SCOPE_AGENT);
            __hip_atomic_store(&pg[256 + i * 8 + iblk], pi,
                               __ATOMIC_RELAXED, __HIP_MEMORY_SCOPE_AGENT);
            asm volatile("s_waitcnt vmcnt(0)" ::: "memory");    // drain (wave 0)
            if (tid == 0)
                __hip_atomic_fetch_add(cnt + (size_t)b * NSTEPS + (t - 1), 1u,
                                       __ATOMIC_RELAXED, __HIP_MEMORY_SCOPE_AGENT);
        }

        // ---- features for t+1 (Sv/DE/ex) — hidden inside the spin window ----
        if (t < NSTEPS) {
            const int curS = 1 - cur;
            const int r = tid >> 3, c = tid & 7;
            const int i = r & 31, j = j0 + (r >> 5);
            float Sv = 0.f;
            #pragma unroll
            for (int m = c; m < NN; m += 8)
                Sv += CpN[curS][i][m] * CpN[1 - curS][j][m];
            Sv += __shfl_xor(Sv, 1); Sv += __shfl_xor(Sv, 2); Sv += __shfl_xor(Sv, 4);
            if (c == 0) {
                const int kj = kkL[curS][j];
                const float DE = (i == kj) ? 0.f : (EL[curS][i] - EL[1 - curS][j]);
                featS[r] = make_float4(DE, 100.f, Sv, __expf(DE / kbt));
            }
        }

        // ---- sibling barrier: wait for 8 arrivals ----
        if (tid == 0) {
            const unsigned int* c = cnt + (size_t)b * NSTEPS + (t - 1);
            while (__hip_atomic_load(c, __ATOMIC_RELAXED, __HIP_MEMORY_SCOPE_AGENT)
                   < (unsigned)NIB) {
                __builtin_amdgcn_s_sleep(2);    // ~128cyc between polls
            }
        }
        __syncthreads();

        // ---- gather partials: tid = comp*256 + i*8 + sib; 3-level sib-sum ----
        if (tid < 512) {
            const double* pg = part_g + ((size_t)cur * NB + b) * 512;
            double v = __hip_atomic_load(&pg[tid], __ATOMIC_RELAXED,
                                         __HIP_MEMORY_SCOPE_AGENT);
            v += __shfl_xor(v, 1); v += __shfl_xor(v, 2); v += __shfl_xor(v, 4);
            if ((tid & 7) == 0) {
                const int i = (tid >> 3) & 31;
                if (tid < 256) sre[i] = v; else sim[i] = v;
            }
        }
        __syncthreads();

        // ---- fused phase + normalize (wave 0) ----
        if (tid < NN) {
            const int ii = tid;
            double are = sre[ii], aim = sim[ii];
            double th = (double)EL[cur][ii] * (TWO_PI * ICM2IFS) * dtb;   // |th| < ~0.1
            double x2 = th * th;        // poly sincos, |err| ~1e-16 at this range
            double sph = th * (1.0 + x2 * (-1.0 / 6.0 + x2 * (1.0 / 120.0 + x2 * (-1.0 / 5040.0 + x2 * (1.0 / 362880.0)))));
            double cph = 1.0 + x2 * (-0.5 + x2 * (1.0 / 24.0 + x2 * (-1.0 / 720.0 + x2 * (1.0 / 40320.0))));
            double nre = cph * are + sph * aim;            // exp(-iEw) = c - i s
            double nim = cph * aim - sph * are;
            double v = nre * nre + nim * nim;
            double s = v;
            s += __shfl_xor(s, 1); s += __shfl_xor(s, 2); s += __shfl_xor(s, 4);
            s += __shfl_xor(s, 8); s += __shfl_xor(s, 16);
            double sc = 1.0 / sqrt(s);
            double nr = nre * sc, ni = nim * sc;
            phre[ii] = nr; phim[ii] = ni;
            phi2l[ii] = (float)(nr * nr + ni * ni);
        }
        __syncthreads();

        // ---- ploc (every NSI steps, 4 rows per sibling) + ratio finalize ----
        if ((t % NSI) == 0 && tid < 64) {
            const int ii = iblk * 4 + (tid >> 4), l = tid & 15;
            double are = 0.0, aim = 0.0;
            #pragma unroll
            for (int jj = l; jj < NN; jj += 16) {
                double cij = (double)CpN[cur][jj][ii];   // C_t[i][j] = CT_t[j][i]
                are += cij * phre[jj]; aim += cij * phim[jj];
            }
            are += __shfl_xor(are, 1); aim += __shfl_xor(aim, 1);
            are += __shfl_xor(are, 2); aim += __shfl_xor(aim, 2);
            are += __shfl_xor(are, 4); aim += __shfl_xor(aim, 4);
            are += __shfl_xor(are, 8); aim += __shfl_xor(aim, 8);
            if (l == 0)
                out[((size_t)b * 61 + t / NSI) * NN + ii] = (float)(are * are + aim * aim);
        }
        if (t < NSTEPS && tid < 128) {     // ratio for t+1 (needs fresh phi2l)
            const int i = tid & 31, j = j0 + (tid >> 5);
            const float p_i = phi2l[i], p_j = phi2l[j];
            featS[tid].y = (p_j > 0.01f * p_i) ? (p_i / p_j) : 100.f;
        }
    }
}

// ---------------------------------------------------------------------------
extern "C" void kernel_launch(void* const* d_in, const int* in_sizes, int n_in,
                              void* d_out, int out_size, void* d_ws, size_t ws_size,
                              hipStream_t stream)
{
    const float* Tarr = (const float*)d_in[0];
    const float* ErA  = (const float*)d_in[1];
    const float* ctA  = (const float*)d_in[2];
    const float* dtA  = (const float*)d_in[4];
    const float* psi0 = (const float*)d_in[6];
    const float* Hf   = (const float*)d_in[7];
    const float* W1   = (const float*)d_in[8];
    const float* b1   = (const float*)d_in[9];
    const float* W2   = (const float*)d_in[10];
    const float* b2   = (const float*)d_in[11];
    const float* W3   = (const float*)d_in[12];
    const float* b3   = (const float*)d_in[13];
    const float* W4   = (const float*)d_in[14];
    const float* b4   = (const float*)d_in[15];

    unsigned int* cnt = (unsigned int*)d_ws;                    // 32*600 counters
    float* E_all  = (float*)(cnt + (size_t)NB * NSTEPS);        // 32*601*32
    float* CT_all = E_all + (size_t)NB * NT1 * NN;              // 32*601*32*32
    float* W2p    = CT_all + (size_t)NB * NT1 * NN * NN;        // 10240
    float* W3p    = W2p + NG * NKB * 32;                        // 10240
    float4* L1W4  = (float4*)(W3p + NG * NKB * 32);             // 80 f4
    float4* L1B4  = L1W4 + NU;                                  // 80 f4
    float* bpad   = (float*)(L1B4 + NU);                        // 3*80
    double* part_g = (double*)(bpad + 3 * NU);                  // 2*32*512 f64 (256KB)
    int*   kk_all = (int*)(part_g + 2 * (size_t)NB * 512);      // 32*600*32
    float* outp   = (float*)d_out;

    hipMemsetAsync(cnt, 0, (size_t)NB * NSTEPS * sizeof(unsigned int), stream);
    eigh_kernel<<<NB * NT1, 128, 0, stream>>>(Hf, E_all, CT_all);
    wtrans_kernel<<<1, 256, 0, stream>>>(W1, b1, W2, W3, b2, b3, W4,
                                         W2p, W3p, L1W4, L1B4, bpad);
    kk_kernel<<<NB * NSTEPS, 256, 0, stream>>>(CT_all, kk_all);

    // dyn LDS: two f4 tables (80 each) + 4x80 biases + hbuf 80*128
    const size_t dynf = (size_t)(8 * NU) + 4 * NU + NU * 128;
    persist_kernel<<<NB * NIB, 1024, dynf * sizeof(float), stream>>>(E_all, CT_all,
        kk_all, psi0, Tarr, ErA, ctA, dtA, W2p, W3p, L1W4, L1B4, bpad, b4,
        part_g, cnt, outp);
}